// Round 11
// baseline (271.681 us; speedup 1.0000x reference)
//
#include <hip/hip_runtime.h>

#define NN 8192
#define WW_ 128
#define EPSF 1e-8f

// ws float offsets
#define S_LOGITS 0
#define S_ALLOC  8192
#define S_WW     16384
#define S_RET    24576
#define S_G      32768
#define S_RANK   40960
#define S_RC     49152      // 8192*4 -> ends 81920
#define S_SCAL   81920      // 32 scalars
#define S_FWD    90112      // fallback 8192*4
#define S_BWD    122880     // fallback 8192*4
#define S_BWDF   163840     // final bwd 32768 floats -> ends 196608
#define S_FWDP2  524288     // 128 slots * 32768 = 4194304 floats (16 MB) -> ends 4718592
#define WS_NEED2 ((size_t)4718592 * 4)   // 18.87 MB (proven available)

// output float offsets
#define O_RV 0
#define O_NM 512
#define O_NU 1049088
#define O_NP 1057280
#define O_NL 1065472
#define O_NR 68174336

// scratch carved out of the (not-yet-written) new_link output region
#define P_APART 0           // 16*8192
#define P_CPART 131072      // 16*8192
#define P_RVP   262144      // 256*512 rv partials

// ---- zero the scalar accumulators ----
__global__ void k_zero(float* __restrict__ scal) {
    if (threadIdx.x < 32) scal[threadIdx.x] = 0.f;
}

// ---- per-row: content logits, retention, read_vectors partials (no atomics) ----
__global__ __launch_bounds__(256, 4) void k_rowstats(
    const float* __restrict__ mem, const float* __restrict__ rw,
    const float* __restrict__ wk, const float* __restrict__ fg,
    const float* __restrict__ wstr,
    float* __restrict__ rvp, float* __restrict__ logits, float* __restrict__ ret,
    float* __restrict__ scal)
{
    __shared__ float sb[4][512];
    int lane = threadIdx.x & 63;
    int w = threadIdx.x >> 6;
    int wave = (blockIdx.x << 2) + w;            // 0..1023
    int c = lane * 2;
    float2 wk2 = *(const float2*)&wk[c];
    float4 fg4 = *(const float4*)&fg[0];
    float ws = wstr[0];
    float nw = wk2.x * wk2.x + wk2.y * wk2.y;
    #pragma unroll
    for (int s = 1; s < 64; s <<= 1) nw += __shfl_xor(nw, s);
    float wkn = sqrtf(nw);

    float arv[2][4];
    #pragma unroll
    for (int a = 0; a < 2; a++)
        #pragma unroll
        for (int r = 0; r < 4; r++) arv[a][r] = 0.f;
    float se = 0.f;
    int i0 = wave * 8;
    for (int t = 0; t < 8; t++) {
        int i = i0 + t;
        float2 m2 = *(const float2*)&mem[i * WW_ + c];
        float4 rwi = *(const float4*)&rw[i * 4];
        float dp = m2.x * wk2.x + m2.y * wk2.y;
        float nq = m2.x * m2.x + m2.y * m2.y;
        #pragma unroll
        for (int s = 1; s < 64; s <<= 1) { dp += __shfl_xor(dp, s); nq += __shfl_xor(nq, s); }
        arv[0][0] += m2.x * rwi.x; arv[0][1] += m2.x * rwi.y; arv[0][2] += m2.x * rwi.z; arv[0][3] += m2.x * rwi.w;
        arv[1][0] += m2.y * rwi.x; arv[1][1] += m2.y * rwi.y; arv[1][2] += m2.y * rwi.z; arv[1][3] += m2.y * rwi.w;
        if (lane == 0) {
            float denom = fmaxf(sqrtf(nq) * wkn, EPSF);
            float lg = dp / denom * ws;
            logits[i] = lg;
            ret[i] = (1.f - rwi.x * fg4.x) * (1.f - rwi.y * fg4.y) *
                     (1.f - rwi.z * fg4.z) * (1.f - rwi.w * fg4.w);
            se += __expf(lg);
        }
    }
    if (lane == 0) atomicAdd(&scal[6], se);
    #pragma unroll
    for (int a = 0; a < 2; a++)
        #pragma unroll
        for (int r = 0; r < 4; r++)
            sb[w][(c + a) * 4 + r] = arv[a][r];
    __syncthreads();
    for (int idx = threadIdx.x; idx < 512; idx += 256)
        rvp[blockIdx.x * 512 + idx] = sb[0][idx] + sb[1][idx] + sb[2][idx] + sb[3][idx];
}

// ---- allocation partials (masked products + rank counts); also zeroes fallback fwd/bwd ----
__global__ __launch_bounds__(256) void k_apart(const float* __restrict__ u,
                                               float* __restrict__ apart,
                                               float* __restrict__ cpart,
                                               float* __restrict__ fbzero) {
    __shared__ float su[512];
    int gtid = blockIdx.x * 256 + threadIdx.x;
    if (gtid < 65536) fbzero[gtid] = 0.f;
    int jc = blockIdx.x >> 5;
    int ib = blockIdx.x & 31;
    int t = threadIdx.x;
    for (int q = t; q < 512; q += 256) su[q] = u[jc * 512 + q];
    __syncthreads();
    int i = ib * 256 + t;
    float ui = u[i];
    float p0 = 1.f, p1 = 1.f, p2 = 1.f, p3 = 1.f;
    int c0 = 0, c1 = 0, c2 = 0, c3 = 0;
    int jbase = jc * 512;
    for (int q = 0; q < 512; q += 4) {
        float a0 = su[q], a1 = su[q + 1], a2 = su[q + 2], a3 = su[q + 3];
        int j0 = jbase + q;
        bool m0 = (a0 < ui) || (a0 == ui && j0     < i);
        bool m1 = (a1 < ui) || (a1 == ui && j0 + 1 < i);
        bool m2 = (a2 < ui) || (a2 == ui && j0 + 2 < i);
        bool m3 = (a3 < ui) || (a3 == ui && j0 + 3 < i);
        p0 *= m0 ? a0 : 1.f; c0 += m0;
        p1 *= m1 ? a1 : 1.f; c1 += m1;
        p2 *= m2 ? a2 : 1.f; c2 += m2;
        p3 *= m3 ? a3 : 1.f; c3 += m3;
    }
    apart[jc * NN + i] = (p0 * p1) * (p2 * p3);
    cpart[jc * NN + i] = (float)((c0 + c1) + (c2 + c3));
}

// ---- combine partials -> g[i], rank[i], sum(g); blocks 0,1 also reduce rv ----
__global__ __launch_bounds__(256) void k_grank(
    const float* __restrict__ u, const float* __restrict__ apart,
    const float* __restrict__ cpart, const float* __restrict__ rvp,
    float* __restrict__ g, int* __restrict__ rank,
    float* __restrict__ scal, float* __restrict__ rv_out) {
    __shared__ float sb[256];
    int i = blockIdx.x * 256 + threadIdx.x;
    float p = 1.f, c = 0.f;
    #pragma unroll
    for (int jc = 0; jc < 16; jc++) { p *= apart[jc * NN + i]; c += cpart[jc * NN + i]; }
    float gi = (1.f - u[i]) * p;
    g[i] = gi;
    rank[i] = (int)c;
    sb[threadIdx.x] = gi; __syncthreads();
    for (int s = 128; s > 0; s >>= 1) { if (threadIdx.x < s) sb[threadIdx.x] += sb[threadIdx.x + s]; __syncthreads(); }
    if (threadIdx.x == 0) atomicAdd(&scal[8], sb[0]);
    if (blockIdx.x < 2) {
        int idx = blockIdx.x * 256 + threadIdx.x;
        float acc = 0.f;
        for (int pb = 0; pb < 256; pb++) acc += rvp[pb * 512 + idx];
        rv_out[idx] = acc;
    }
}

// ---- reference's alloc_sorted[order] gather == out[rank[rank[m]]] = g[m] ----
__global__ void k_scatter(const float* __restrict__ g, const int* __restrict__ rank,
                          float* __restrict__ alloc) {
    int m = blockIdx.x * 256 + threadIdx.x;
    alloc[rank[rank[m]]] = g[m];
}

// ---- per-row epilogue: ww (inline), new_memory, usage, precedence, read_content ----
__global__ __launch_bounds__(256, 4) void k_rownew(
    const float* __restrict__ mem, const float* __restrict__ logits,
    const float* __restrict__ alloc, const float* __restrict__ u,
    const float* __restrict__ ret, const float* __restrict__ prec,
    const float* __restrict__ er, const float* __restrict__ wv,
    const float* __restrict__ rk, const float* __restrict__ rstr,
    const float* __restrict__ ag, const float* __restrict__ wg_,
    const float* __restrict__ scal,
    float* __restrict__ ww_out, float* __restrict__ nm_out,
    float* __restrict__ nu_out, float* __restrict__ np_out, float* __restrict__ rc_out)
{
    int lane = threadIdx.x & 63;
    int wave = (blockIdx.x << 2) + (threadIdx.x >> 6);
    int c = lane * 2;
    float2 er2 = *(const float2*)&er[c];
    float2 wv2 = *(const float2*)&wv[c];
    float4 rka = *(const float4*)&rk[c * 4];
    float4 rkb = *(const float4*)&rk[(c + 1) * 4];
    float4 rs4 = *(const float4*)&rstr[0];
    float n0 = rka.x * rka.x + rkb.x * rkb.x;
    float n1 = rka.y * rka.y + rkb.y * rkb.y;
    float n2 = rka.z * rka.z + rkb.z * rkb.z;
    float n3 = rka.w * rka.w + rkb.w * rkb.w;
    #pragma unroll
    for (int s = 1; s < 64; s <<= 1) {
        n0 += __shfl_xor(n0, s); n1 += __shfl_xor(n1, s);
        n2 += __shfl_xor(n2, s); n3 += __shfl_xor(n3, s);
    }
    float rkn0 = sqrtf(n0), rkn1 = sqrtf(n1), rkn2 = sqrtf(n2), rkn3 = sqrtf(n3);
    float invS = 1.f / scal[6];
    float Sg = scal[8];
    float ga = ag[0], wg = wg_[0];
    float wsum = wg * (ga * Sg + (1.f - ga));
    int i0 = wave * 4;
    for (int t = 0; t < 4; t++) {
        int i = i0 + t;
        float wwi = wg * (ga * alloc[i] + (1.f - ga) * __expf(logits[i]) * invS);
        float2 m2 = *(const float2*)&mem[i * WW_ + c];
        float nx = m2.x * (1.f - wwi * er2.x) + wwi * wv2.x;
        float ny = m2.y * (1.f - wwi * er2.y) + wwi * wv2.y;
        float2 nm2; nm2.x = nx; nm2.y = ny;
        *(float2*)&nm_out[i * WW_ + c] = nm2;
        float nq = nx * nx + ny * ny;
        float d0 = nx * rka.x + ny * rkb.x;
        float d1 = nx * rka.y + ny * rkb.y;
        float d2 = nx * rka.z + ny * rkb.z;
        float d3 = nx * rka.w + ny * rkb.w;
        #pragma unroll
        for (int s = 1; s < 64; s <<= 1) {
            nq += __shfl_xor(nq, s);
            d0 += __shfl_xor(d0, s); d1 += __shfl_xor(d1, s);
            d2 += __shfl_xor(d2, s); d3 += __shfl_xor(d3, s);
        }
        if (lane == 0) {
            float nrm = sqrtf(nq);
            float l0 = d0 / (nrm * rkn0) * rs4.x;
            float l1 = d1 / (nrm * rkn1) * rs4.y;
            float l2 = d2 / (nrm * rkn2) * rs4.z;
            float l3 = d3 / (nrm * rkn3) * rs4.w;
            float m4 = fmaxf(fmaxf(l0, l1), fmaxf(l2, l3));
            float e0 = __expf(l0 - m4), e1 = __expf(l1 - m4);
            float e2 = __expf(l2 - m4), e3 = __expf(l3 - m4);
            float si = 1.f / (e0 + e1 + e2 + e3);
            float4 rc; rc.x = e0 * si; rc.y = e1 * si; rc.z = e2 * si; rc.w = e3 * si;
            *(float4*)&rc_out[i * 4] = rc;
            ww_out[i] = wwi;
            float ui = u[i];
            nu_out[i] = (ui + wwi - ui * wwi) * ret[i];
            np_out[i] = (1.f - wsum) * prec[i] + wwi;
        }
    }
}

// ==== PASS 1: k_stream — pure copy-shaped stream + register-only fwd accumulation ====
// No LDS, no shuffles. 1024 blocks x 256 thr; thread owns fixed col, 64 sequential sweeps.
__global__ __launch_bounds__(256, 4) void k_stream(
    const float* __restrict__ link, const float* __restrict__ ww,
    const float* __restrict__ prec, const float* __restrict__ rw,
    float* __restrict__ nl_out, float* __restrict__ fwdp)
{
    const int tid = blockIdx.x * 256 + threadIdx.x;    // 0..262143
    const int j4 = tid & 2047;
    const int i0 = tid >> 11;                           // 0..127 (block-uniform)
    const int col = j4 * 4;
    const float4* L4  = (const float4*)link;
    const float4* RW4 = (const float4*)rw;
    float4* NL4 = (float4*)nl_out;

    const float4 wwj = *(const float4*)&ww[col];
    const float4 pj  = *(const float4*)&prec[col];

    float4 acc0, acc1, acc2, acc3;     // fwd acc per owned col, components = r
    acc0.x = acc0.y = acc0.z = acc0.w = 0.f;
    acc1 = acc0; acc2 = acc0; acc3 = acc0;

    #pragma unroll 8
    for (int k = 0; k < 64; ++k) {
        const int i = i0 + (k << 7);
        const float wwi = ww[i];
        const float4 rwi = RW4[i];
        const size_t v = (size_t)tid + ((size_t)k << 18);
        const float4 Lv = L4[v];
        const float cc = 1.f - wwi;
        float4 e;
        e.x = (cc - wwj.x) * Lv.x + wwi * pj.x;
        e.y = (cc - wwj.y) * Lv.y + wwi * pj.y;
        e.z = (cc - wwj.z) * Lv.z + wwi * pj.z;
        e.w = (cc - wwj.w) * Lv.w + wwi * pj.w;
        NL4[v] = e;
        acc0.x += e.x * rwi.x; acc0.y += e.x * rwi.y; acc0.z += e.x * rwi.z; acc0.w += e.x * rwi.w;
        acc1.x += e.y * rwi.x; acc1.y += e.y * rwi.y; acc1.z += e.y * rwi.z; acc1.w += e.y * rwi.w;
        acc2.x += e.z * rwi.x; acc2.y += e.z * rwi.y; acc2.z += e.z * rwi.z; acc2.w += e.z * rwi.w;
        acc3.x += e.w * rwi.x; acc3.y += e.w * rwi.y; acc3.z += e.w * rwi.z; acc3.w += e.w * rwi.w;
    }
    float4* fp = (float4*)fwdp + (size_t)i0 * NN + col;
    fp[0] = acc0; fp[1] = acc1; fp[2] = acc2; fp[3] = acc3;
}

// ==== PASS 2: k_bwd — read-only row reduction over new_link (shuffles amortized per row) ====
// 1024 blocks x 4 waves; wave handles 2 consecutive rows.
__global__ __launch_bounds__(256, 4) void k_bwd(
    const float* __restrict__ nl, const float* __restrict__ rw,
    float* __restrict__ bwdF)
{
    const int lane = threadIdx.x & 63;
    const int w = threadIdx.x >> 6;
    const int gw = blockIdx.x * 4 + w;       // 0..4095
    const int i = gw * 2;
    const float4* E4  = (const float4*)nl;
    const float4* RW4 = (const float4*)rw;

    float4 b0, b1;                            // components = r
    b0.x = b0.y = b0.z = b0.w = 0.f; b1 = b0;

    const float4* row0 = E4 + (size_t)i * 2048;
    const float4* row1 = row0 + 2048;

    #pragma unroll 4
    for (int s = 0; s < 32; ++s) {
        const int jj = s * 64 + lane;         // vec4 col index
        const float4 e0 = row0[jj];
        const float4 e1 = row1[jj];
        const float4 r0 = RW4[jj * 4 + 0];
        const float4 r1 = RW4[jj * 4 + 1];
        const float4 r2 = RW4[jj * 4 + 2];
        const float4 r3 = RW4[jj * 4 + 3];
        b0.x += e0.x * r0.x + e0.y * r1.x + e0.z * r2.x + e0.w * r3.x;
        b0.y += e0.x * r0.y + e0.y * r1.y + e0.z * r2.y + e0.w * r3.y;
        b0.z += e0.x * r0.z + e0.y * r1.z + e0.z * r2.z + e0.w * r3.z;
        b0.w += e0.x * r0.w + e0.y * r1.w + e0.z * r2.w + e0.w * r3.w;
        b1.x += e1.x * r0.x + e1.y * r1.x + e1.z * r2.x + e1.w * r3.x;
        b1.y += e1.x * r0.y + e1.y * r1.y + e1.z * r2.y + e1.w * r3.y;
        b1.z += e1.x * r0.z + e1.y * r1.z + e1.z * r2.z + e1.w * r3.z;
        b1.w += e1.x * r0.w + e1.y * r1.w + e1.z * r2.w + e1.w * r3.w;
    }
    // reduce each row's (r0..r3) across 64 lanes: pair-merge (3 shfl) + butterfly (4 shfl)
    #pragma unroll
    for (int q = 0; q < 2; ++q) {
        const float4 b = q ? b1 : b0;
        float u01 = (lane & 1) ? b.x : b.y;
        float v01 = __shfl_xor(u01, 1);
        float A = ((lane & 1) ? b.y : b.x) + v01;
        float u23 = (lane & 1) ? b.z : b.w;
        float v23 = __shfl_xor(u23, 1);
        float B = ((lane & 1) ? b.w : b.z) + v23;
        float uu = (lane & 2) ? A : B;
        float vv = __shfl_xor(uu, 2);
        float S = ((lane & 2) ? B : A) + vv;      // lane 4g+r: r-comp over group g
        #pragma unroll
        for (int s = 4; s < 64; s <<= 1) S += __shfl_xor(S, s);
        if (lane < 4) bwdF[(i + q) * 4 + lane] = S;
    }
}

// ---- reduce 128 fwd slots + combine with final bwd into new read weightings ----
__global__ __launch_bounds__(256) void k_final7(
    const float* __restrict__ fwdp, const float* __restrict__ bwdF,
    const float* __restrict__ rc, const float* __restrict__ modes,
    float* __restrict__ out) {
    __shared__ float fs[4][64];
    const int lane = threadIdx.x & 63;
    const int w = threadIdx.x >> 6;
    const int o = blockIdx.x * 64 + lane;    // grid 512 -> 32768
    float f = 0.f;
    #pragma unroll
    for (int k = 0; k < 32; ++k) f += fwdp[(size_t)(w * 32 + k) * (NN * 4) + o];
    fs[w][lane] = f;
    __syncthreads();
    if (threadIdx.x < 64) {
        const float F = (fs[0][lane] + fs[1][lane]) + (fs[2][lane] + fs[3][lane]);
        const int r = o & 3;
        out[o] = bwdF[o] * modes[r * 3] + rc[o] * modes[r * 3 + 1] + F * modes[r * 3 + 2];
    }
}

// ==== fallback (round-4, proven) k_link + k_final ====
__global__ __launch_bounds__(256, 4) void k_link(
    const float* __restrict__ link, const float* __restrict__ ww,
    const float* __restrict__ prec, const float* __restrict__ rw,
    float* __restrict__ nl_out, float* __restrict__ fwd, float* __restrict__ bwd)
{
    __shared__ float part[64][16][4];
    __shared__ float fl[4][256][4];
    const int lane = threadIdx.x & 63;
    const int w = threadIdx.x >> 6;
    const int j = blockIdx.x * 256 + lane * 4;
    const float4 wwj = *(const float4*)&ww[j];
    const float4 pj  = *(const float4*)&prec[j];
    const float4 rwj0 = *(const float4*)&rw[j * 4];
    const float4 rwj1 = *(const float4*)&rw[j * 4 + 4];
    const float4 rwj2 = *(const float4*)&rw[j * 4 + 8];
    const float4 rwj3 = *(const float4*)&rw[j * 4 + 12];
    float fa[4][4];
    #pragma unroll
    for (int a = 0; a < 4; a++)
        #pragma unroll
        for (int r = 0; r < 4; r++) fa[a][r] = 0.f;
    for (int sub = 0; sub < 4; ++sub) {
        const int i00 = blockIdx.y * 256 + sub * 64;
        const int irow0 = i00 + w * 16;
        #pragma unroll 4
        for (int t = 0; t < 16; ++t) {
            const int i = irow0 + t;
            const float wwi = ww[i];
            const float4 rwi = *(const float4*)&rw[i * 4];
            const size_t off = (size_t)i * NN + j;
            const float4 Lv = *(const float4*)&link[off];
            const float c0 = 1.f - wwi;
            float4 e;
            e.x = (c0 - wwj.x) * Lv.x + wwi * pj.x;
            e.y = (c0 - wwj.y) * Lv.y + wwi * pj.y;
            e.z = (c0 - wwj.z) * Lv.z + wwi * pj.z;
            e.w = (c0 - wwj.w) * Lv.w + wwi * pj.w;
            *(float4*)&nl_out[off] = e;
            fa[0][0] += e.x * rwi.x; fa[0][1] += e.x * rwi.y; fa[0][2] += e.x * rwi.z; fa[0][3] += e.x * rwi.w;
            fa[1][0] += e.y * rwi.x; fa[1][1] += e.y * rwi.y; fa[1][2] += e.y * rwi.z; fa[1][3] += e.y * rwi.w;
            fa[2][0] += e.z * rwi.x; fa[2][1] += e.z * rwi.y; fa[2][2] += e.z * rwi.z; fa[2][3] += e.z * rwi.w;
            fa[3][0] += e.w * rwi.x; fa[3][1] += e.w * rwi.y; fa[3][2] += e.w * rwi.z; fa[3][3] += e.w * rwi.w;
            float b0 = e.x * rwj0.x + e.y * rwj1.x + e.z * rwj2.x + e.w * rwj3.x;
            float b1 = e.x * rwj0.y + e.y * rwj1.y + e.z * rwj2.y + e.w * rwj3.y;
            float b2 = e.x * rwj0.z + e.y * rwj1.z + e.z * rwj2.z + e.w * rwj3.z;
            float b3 = e.x * rwj0.w + e.y * rwj1.w + e.z * rwj2.w + e.w * rwj3.w;
            float u01 = (lane & 1) ? b0 : b1;
            float v01 = __shfl_xor(u01, 1);
            float A = ((lane & 1) ? b1 : b0) + v01;
            float u23 = (lane & 1) ? b2 : b3;
            float v23 = __shfl_xor(u23, 1);
            float B = ((lane & 1) ? b3 : b2) + v23;
            float uu = (lane & 2) ? A : B;
            float vv = __shfl_xor(uu, 2);
            float S = ((lane & 2) ? B : A) + vv;
            #pragma unroll
            for (int s = 4; s < 64; s <<= 1) S += __shfl_xor(S, s);
            const int row = w * 16 + t;
            if (lane < 4) part[row][((lane >> 2) + row) & 15][lane & 3] = S;
        }
        __syncthreads();
        if (threadIdx.x < 64) {
            const int row = threadIdx.x;
            float4 acc; acc.x = 0.f; acc.y = 0.f; acc.z = 0.f; acc.w = 0.f;
            #pragma unroll
            for (int k = 0; k < 16; ++k) {
                const float4 p = *(const float4*)&part[row][(k + row) & 15][0];
                acc.x += p.x; acc.y += p.y; acc.z += p.z; acc.w += p.w;
            }
            const int i = i00 + row;
            atomicAdd(&bwd[i * 4 + 0], acc.x);
            atomicAdd(&bwd[i * 4 + 1], acc.y);
            atomicAdd(&bwd[i * 4 + 2], acc.z);
            atomicAdd(&bwd[i * 4 + 3], acc.w);
        }
        __syncthreads();
    }
    #pragma unroll
    for (int a = 0; a < 4; a++)
        #pragma unroll
        for (int r = 0; r < 4; r++)
            fl[w][lane * 4 + a][r] = fa[a][r];
    __syncthreads();
    const int col = threadIdx.x;
    const float4 s0 = *(const float4*)&fl[0][col][0];
    const float4 s1 = *(const float4*)&fl[1][col][0];
    const float4 s2 = *(const float4*)&fl[2][col][0];
    const float4 s3 = *(const float4*)&fl[3][col][0];
    atomicAdd(&fwd[(blockIdx.x * 256 + col) * 4 + 0], s0.x + s1.x + s2.x + s3.x);
    atomicAdd(&fwd[(blockIdx.x * 256 + col) * 4 + 1], s0.y + s1.y + s2.y + s3.y);
    atomicAdd(&fwd[(blockIdx.x * 256 + col) * 4 + 2], s0.z + s1.z + s2.z + s3.z);
    atomicAdd(&fwd[(blockIdx.x * 256 + col) * 4 + 3], s0.w + s1.w + s2.w + s3.w);
}

__global__ void k_final(const float* __restrict__ fwd, const float* __restrict__ bwd,
                        const float* __restrict__ rc, const float* __restrict__ modes,
                        float* __restrict__ out) {
    int idx = blockIdx.x * 256 + threadIdx.x;
    int r = idx & 3;
    float m0 = modes[r * 3], m1 = modes[r * 3 + 1], m2 = modes[r * 3 + 2];
    out[idx] = bwd[idx] * m0 + rc[idx] * m1 + fwd[idx] * m2;
}

extern "C" void kernel_launch(void* const* d_in, const int* in_sizes, int n_in,
                              void* d_out, int out_size, void* d_ws, size_t ws_size,
                              hipStream_t stream) {
    const float* mem   = (const float*)d_in[0];
    const float* u     = (const float*)d_in[1];
    const float* prec  = (const float*)d_in[2];
    const float* link  = (const float*)d_in[3];
    const float* rw    = (const float*)d_in[4];
    const float* rk    = (const float*)d_in[5];
    const float* rstr  = (const float*)d_in[6];
    const float* wk    = (const float*)d_in[7];
    const float* wstr  = (const float*)d_in[8];
    const float* er    = (const float*)d_in[9];
    const float* wv    = (const float*)d_in[10];
    const float* fg    = (const float*)d_in[11];
    const float* ag    = (const float*)d_in[12];
    const float* wg    = (const float*)d_in[13];
    const float* modes = (const float*)d_in[14];
    float* out = (float*)d_out;
    float* ws  = (float*)d_ws;
    float* nlr = out + O_NL;

    k_zero<<<1, 64, 0, stream>>>(ws + S_SCAL);
    k_rowstats<<<256, 256, 0, stream>>>(mem, rw, wk, fg, wstr,
                                        nlr + P_RVP, ws + S_LOGITS, ws + S_RET, ws + S_SCAL);
    k_apart<<<512, 256, 0, stream>>>(u, nlr + P_APART, nlr + P_CPART, ws + S_FWD);
    k_grank<<<32, 256, 0, stream>>>(u, nlr + P_APART, nlr + P_CPART, nlr + P_RVP,
                                    ws + S_G, (int*)(ws + S_RANK), ws + S_SCAL, out + O_RV);
    k_scatter<<<32, 256, 0, stream>>>(ws + S_G, (const int*)(ws + S_RANK), ws + S_ALLOC);
    k_rownew<<<512, 256, 0, stream>>>(mem, ws + S_LOGITS, ws + S_ALLOC, u, ws + S_RET,
                                      prec, er, wv, rk, rstr, ag, wg, ws + S_SCAL,
                                      ws + S_WW, out + O_NM, out + O_NU, out + O_NP, ws + S_RC);

    if (ws_size >= WS_NEED2) {
        k_stream<<<1024, 256, 0, stream>>>(link, ws + S_WW, prec, rw, out + O_NL, ws + S_FWDP2);
        k_bwd<<<1024, 256, 0, stream>>>(out + O_NL, rw, ws + S_BWDF);
        k_final7<<<512, 256, 0, stream>>>(ws + S_FWDP2, ws + S_BWDF, ws + S_RC, modes, out + O_NR);
    } else {
        dim3 lg(32, 32);
        k_link<<<lg, 256, 0, stream>>>(link, ws + S_WW, prec, rw, out + O_NL,
                                       ws + S_FWD, ws + S_BWD);
        k_final<<<128, 256, 0, stream>>>(ws + S_FWD, ws + S_BWD, ws + S_RC, modes, out + O_NR);
    }
}

// Round 12
// 181.542 us; speedup vs baseline: 1.4965x; 1.4965x over previous
//
#include <hip/hip_runtime.h>

#define NN 8192
#define WW_ 128
#define EPSF 1e-8f

// ws float offsets
#define S_LOGITS 0
#define S_ALLOC  8192
#define S_WW     16384
#define S_RET    24576
#define S_G      32768
#define S_RANK   40960
#define S_RC     49152      // 8192*4 -> ends 81920
#define S_SCAL   81920      // 32 scalars
#define S_FWD    90112      // fallback 8192*4
#define S_BWD    122880     // fallback 8192*4
#define S_BWDP2  163840     // 8 slots * 32768 (1 MB) -> ends 425984
#define S_FWDP2  524288     // 128 slots * 32768 (16 MB) -> ends 4718592
#define WS_NEED2 ((size_t)4718592 * 4)   // 18.87 MB (proven available)

// output float offsets
#define O_RV 0
#define O_NM 512
#define O_NU 1049088
#define O_NP 1057280
#define O_NL 1065472
#define O_NR 68174336

// scratch carved out of the (not-yet-written) new_link output region
#define P_APART 0           // 16*8192
#define P_CPART 131072      // 16*8192
#define P_RVP   262144      // 256*512 rv partials

__global__ void k_zero(float* __restrict__ scal) {
    if (threadIdx.x < 32) scal[threadIdx.x] = 0.f;
}

// ---- per-row: content logits, retention, read_vectors partials (no atomics) ----
__global__ __launch_bounds__(256, 4) void k_rowstats(
    const float* __restrict__ mem, const float* __restrict__ rw,
    const float* __restrict__ wk, const float* __restrict__ fg,
    const float* __restrict__ wstr,
    float* __restrict__ rvp, float* __restrict__ logits, float* __restrict__ ret,
    float* __restrict__ scal)
{
    __shared__ float sb[4][512];
    int lane = threadIdx.x & 63;
    int w = threadIdx.x >> 6;
    int wave = (blockIdx.x << 2) + w;            // 0..1023
    int c = lane * 2;
    float2 wk2 = *(const float2*)&wk[c];
    float4 fg4 = *(const float4*)&fg[0];
    float ws = wstr[0];
    float nw = wk2.x * wk2.x + wk2.y * wk2.y;
    #pragma unroll
    for (int s = 1; s < 64; s <<= 1) nw += __shfl_xor(nw, s);
    float wkn = sqrtf(nw);

    float arv[2][4];
    #pragma unroll
    for (int a = 0; a < 2; a++)
        #pragma unroll
        for (int r = 0; r < 4; r++) arv[a][r] = 0.f;
    float se = 0.f;
    int i0 = wave * 8;
    for (int t = 0; t < 8; t++) {
        int i = i0 + t;
        float2 m2 = *(const float2*)&mem[i * WW_ + c];
        float4 rwi = *(const float4*)&rw[i * 4];
        float dp = m2.x * wk2.x + m2.y * wk2.y;
        float nq = m2.x * m2.x + m2.y * m2.y;
        #pragma unroll
        for (int s = 1; s < 64; s <<= 1) { dp += __shfl_xor(dp, s); nq += __shfl_xor(nq, s); }
        arv[0][0] += m2.x * rwi.x; arv[0][1] += m2.x * rwi.y; arv[0][2] += m2.x * rwi.z; arv[0][3] += m2.x * rwi.w;
        arv[1][0] += m2.y * rwi.x; arv[1][1] += m2.y * rwi.y; arv[1][2] += m2.y * rwi.z; arv[1][3] += m2.y * rwi.w;
        if (lane == 0) {
            float denom = fmaxf(sqrtf(nq) * wkn, EPSF);
            float lg = dp / denom * ws;
            logits[i] = lg;
            ret[i] = (1.f - rwi.x * fg4.x) * (1.f - rwi.y * fg4.y) *
                     (1.f - rwi.z * fg4.z) * (1.f - rwi.w * fg4.w);
            se += __expf(lg);
        }
    }
    if (lane == 0) atomicAdd(&scal[6], se);
    #pragma unroll
    for (int a = 0; a < 2; a++)
        #pragma unroll
        for (int r = 0; r < 4; r++)
            sb[w][(c + a) * 4 + r] = arv[a][r];
    __syncthreads();
    for (int idx = threadIdx.x; idx < 512; idx += 256)
        rvp[blockIdx.x * 512 + idx] = sb[0][idx] + sb[1][idx] + sb[2][idx] + sb[3][idx];
}

// ---- allocation partials; also zeroes fallback fwd/bwd ----
__global__ __launch_bounds__(256) void k_apart(const float* __restrict__ u,
                                               float* __restrict__ apart,
                                               float* __restrict__ cpart,
                                               float* __restrict__ fbzero) {
    __shared__ float su[512];
    int gtid = blockIdx.x * 256 + threadIdx.x;
    if (gtid < 65536) fbzero[gtid] = 0.f;
    int jc = blockIdx.x >> 5;
    int ib = blockIdx.x & 31;
    int t = threadIdx.x;
    for (int q = t; q < 512; q += 256) su[q] = u[jc * 512 + q];
    __syncthreads();
    int i = ib * 256 + t;
    float ui = u[i];
    float p0 = 1.f, p1 = 1.f, p2 = 1.f, p3 = 1.f;
    int c0 = 0, c1 = 0, c2 = 0, c3 = 0;
    int jbase = jc * 512;
    for (int q = 0; q < 512; q += 4) {
        float a0 = su[q], a1 = su[q + 1], a2 = su[q + 2], a3 = su[q + 3];
        int j0 = jbase + q;
        bool m0 = (a0 < ui) || (a0 == ui && j0     < i);
        bool m1 = (a1 < ui) || (a1 == ui && j0 + 1 < i);
        bool m2 = (a2 < ui) || (a2 == ui && j0 + 2 < i);
        bool m3 = (a3 < ui) || (a3 == ui && j0 + 3 < i);
        p0 *= m0 ? a0 : 1.f; c0 += m0;
        p1 *= m1 ? a1 : 1.f; c1 += m1;
        p2 *= m2 ? a2 : 1.f; c2 += m2;
        p3 *= m3 ? a3 : 1.f; c3 += m3;
    }
    apart[jc * NN + i] = (p0 * p1) * (p2 * p3);
    cpart[jc * NN + i] = (float)((c0 + c1) + (c2 + c3));
}

// ---- combine partials -> g[i], rank[i], sum(g); blocks 0,1 also reduce rv ----
__global__ __launch_bounds__(256) void k_grank(
    const float* __restrict__ u, const float* __restrict__ apart,
    const float* __restrict__ cpart, const float* __restrict__ rvp,
    float* __restrict__ g, int* __restrict__ rank,
    float* __restrict__ scal, float* __restrict__ rv_out) {
    __shared__ float sb[256];
    int i = blockIdx.x * 256 + threadIdx.x;
    float p = 1.f, c = 0.f;
    #pragma unroll
    for (int jc = 0; jc < 16; jc++) { p *= apart[jc * NN + i]; c += cpart[jc * NN + i]; }
    float gi = (1.f - u[i]) * p;
    g[i] = gi;
    rank[i] = (int)c;
    sb[threadIdx.x] = gi; __syncthreads();
    for (int s = 128; s > 0; s >>= 1) { if (threadIdx.x < s) sb[threadIdx.x] += sb[threadIdx.x + s]; __syncthreads(); }
    if (threadIdx.x == 0) atomicAdd(&scal[8], sb[0]);
    if (blockIdx.x < 2) {
        int idx = blockIdx.x * 256 + threadIdx.x;
        float acc = 0.f;
        for (int pb = 0; pb < 256; pb++) acc += rvp[pb * 512 + idx];
        rv_out[idx] = acc;
    }
}

// ---- reference's alloc_sorted[order] gather == out[rank[rank[m]]] = g[m] ----
__global__ void k_scatter(const float* __restrict__ g, const int* __restrict__ rank,
                          float* __restrict__ alloc) {
    int m = blockIdx.x * 256 + threadIdx.x;
    alloc[rank[rank[m]]] = g[m];
}

// ---- per-row epilogue ----
__global__ __launch_bounds__(256, 4) void k_rownew(
    const float* __restrict__ mem, const float* __restrict__ logits,
    const float* __restrict__ alloc, const float* __restrict__ u,
    const float* __restrict__ ret, const float* __restrict__ prec,
    const float* __restrict__ er, const float* __restrict__ wv,
    const float* __restrict__ rk, const float* __restrict__ rstr,
    const float* __restrict__ ag, const float* __restrict__ wg_,
    const float* __restrict__ scal,
    float* __restrict__ ww_out, float* __restrict__ nm_out,
    float* __restrict__ nu_out, float* __restrict__ np_out, float* __restrict__ rc_out)
{
    int lane = threadIdx.x & 63;
    int wave = (blockIdx.x << 2) + (threadIdx.x >> 6);
    int c = lane * 2;
    float2 er2 = *(const float2*)&er[c];
    float2 wv2 = *(const float2*)&wv[c];
    float4 rka = *(const float4*)&rk[c * 4];
    float4 rkb = *(const float4*)&rk[(c + 1) * 4];
    float4 rs4 = *(const float4*)&rstr[0];
    float n0 = rka.x * rka.x + rkb.x * rkb.x;
    float n1 = rka.y * rka.y + rkb.y * rkb.y;
    float n2 = rka.z * rka.z + rkb.z * rkb.z;
    float n3 = rka.w * rka.w + rkb.w * rkb.w;
    #pragma unroll
    for (int s = 1; s < 64; s <<= 1) {
        n0 += __shfl_xor(n0, s); n1 += __shfl_xor(n1, s);
        n2 += __shfl_xor(n2, s); n3 += __shfl_xor(n3, s);
    }
    float rkn0 = sqrtf(n0), rkn1 = sqrtf(n1), rkn2 = sqrtf(n2), rkn3 = sqrtf(n3);
    float invS = 1.f / scal[6];
    float Sg = scal[8];
    float ga = ag[0], wg = wg_[0];
    float wsum = wg * (ga * Sg + (1.f - ga));
    int i0 = wave * 4;
    for (int t = 0; t < 4; t++) {
        int i = i0 + t;
        float wwi = wg * (ga * alloc[i] + (1.f - ga) * __expf(logits[i]) * invS);
        float2 m2 = *(const float2*)&mem[i * WW_ + c];
        float nx = m2.x * (1.f - wwi * er2.x) + wwi * wv2.x;
        float ny = m2.y * (1.f - wwi * er2.y) + wwi * wv2.y;
        float2 nm2; nm2.x = nx; nm2.y = ny;
        *(float2*)&nm_out[i * WW_ + c] = nm2;
        float nq = nx * nx + ny * ny;
        float d0 = nx * rka.x + ny * rkb.x;
        float d1 = nx * rka.y + ny * rkb.y;
        float d2 = nx * rka.z + ny * rkb.z;
        float d3 = nx * rka.w + ny * rkb.w;
        #pragma unroll
        for (int s = 1; s < 64; s <<= 1) {
            nq += __shfl_xor(nq, s);
            d0 += __shfl_xor(d0, s); d1 += __shfl_xor(d1, s);
            d2 += __shfl_xor(d2, s); d3 += __shfl_xor(d3, s);
        }
        if (lane == 0) {
            float nrm = sqrtf(nq);
            float l0 = d0 / (nrm * rkn0) * rs4.x;
            float l1 = d1 / (nrm * rkn1) * rs4.y;
            float l2 = d2 / (nrm * rkn2) * rs4.z;
            float l3 = d3 / (nrm * rkn3) * rs4.w;
            float m4 = fmaxf(fmaxf(l0, l1), fmaxf(l2, l3));
            float e0 = __expf(l0 - m4), e1 = __expf(l1 - m4);
            float e2 = __expf(l2 - m4), e3 = __expf(l3 - m4);
            float si = 1.f / (e0 + e1 + e2 + e3);
            float4 rc; rc.x = e0 * si; rc.y = e1 * si; rc.z = e2 * si; rc.w = e3 * si;
            *(float4*)&rc_out[i * 4] = rc;
            ww_out[i] = wwi;
            float ui = u[i];
            nu_out[i] = (ui + wwi - ui * wwi) * ret[i];
            np_out[i] = (1.f - wsum) * prec[i] + wwi;
        }
    }
}

// ==== fused k_link6: sequential sweep, fixed-column threads, scalarized row loads ====
__global__ __launch_bounds__(256, 4) void k_link6(
    const float* __restrict__ link, const float* __restrict__ ww,
    const float* __restrict__ prec, const float* __restrict__ rw,
    float* __restrict__ nl_out, float* __restrict__ fwdp, float* __restrict__ bwdp)
{
    __shared__ float part[64][4][4];       // 4 KB
    const int lane = threadIdx.x & 63;
    const int w = threadIdx.x >> 6;
    const int tid = blockIdx.x * 256 + threadIdx.x;    // 0..262143
    const int j4 = tid & 2047;                          // vec4 column
    const int i0 = __builtin_amdgcn_readfirstlane(tid >> 11);   // 0..127, wave-uniform
    const int col = j4 * 4;
    const float4* L4  = (const float4*)link;
    const float4* RW4 = (const float4*)rw;
    float4* NL4 = (float4*)nl_out;

    const float4 wwj = *(const float4*)&ww[col];
    const float4 pj  = *(const float4*)&prec[col];
    const float4 rj0 = RW4[col + 0];
    const float4 rj1 = RW4[col + 1];
    const float4 rj2 = RW4[col + 2];
    const float4 rj3 = RW4[col + 3];
    float4 rwT0, rwT1, rwT2, rwT3;          // rwT[r][c] = rw[col_c][r]
    rwT0.x = rj0.x; rwT0.y = rj1.x; rwT0.z = rj2.x; rwT0.w = rj3.x;
    rwT1.x = rj0.y; rwT1.y = rj1.y; rwT1.z = rj2.y; rwT1.w = rj3.y;
    rwT2.x = rj0.z; rwT2.y = rj1.z; rwT2.z = rj2.z; rwT2.w = rj3.z;
    rwT3.x = rj0.w; rwT3.y = rj1.w; rwT3.z = rj2.w; rwT3.w = rj3.w;

    float4 acc0, acc1, acc2, acc3;
    acc0.x = acc0.y = acc0.z = acc0.w = 0.f;
    acc1 = acc0; acc2 = acc0; acc3 = acc0;

    #pragma unroll 8
    for (int k = 0; k < 64; ++k) {
        const int i = i0 + (k << 7);                    // wave-uniform -> scalar loads
        const float wwi = ww[i];
        const float4 rwi = RW4[i];
        const size_t v = (size_t)tid + ((size_t)k << 18);
        const float4 Lv = L4[v];
        const float cc = 1.f - wwi;
        float4 e;
        e.x = (cc - wwj.x) * Lv.x + wwi * pj.x;
        e.y = (cc - wwj.y) * Lv.y + wwi * pj.y;
        e.z = (cc - wwj.z) * Lv.z + wwi * pj.z;
        e.w = (cc - wwj.w) * Lv.w + wwi * pj.w;
        NL4[v] = e;
        acc0.x += e.x * rwi.x; acc0.y += e.x * rwi.y; acc0.z += e.x * rwi.z; acc0.w += e.x * rwi.w;
        acc1.x += e.y * rwi.x; acc1.y += e.y * rwi.y; acc1.z += e.y * rwi.z; acc1.w += e.y * rwi.w;
        acc2.x += e.z * rwi.x; acc2.y += e.z * rwi.y; acc2.z += e.z * rwi.z; acc2.w += e.z * rwi.w;
        acc3.x += e.w * rwi.x; acc3.y += e.w * rwi.y; acc3.z += e.w * rwi.z; acc3.w += e.w * rwi.w;
        // bwd: 7-shuffle wave reduce of this row's 256-col slice
        float b0 = e.x * rwT0.x + e.y * rwT0.y + e.z * rwT0.z + e.w * rwT0.w;
        float b1 = e.x * rwT1.x + e.y * rwT1.y + e.z * rwT1.z + e.w * rwT1.w;
        float b2 = e.x * rwT2.x + e.y * rwT2.y + e.z * rwT2.z + e.w * rwT2.w;
        float b3 = e.x * rwT3.x + e.y * rwT3.y + e.z * rwT3.z + e.w * rwT3.w;
        float u01 = (lane & 1) ? b0 : b1;
        float v01 = __shfl_xor(u01, 1);
        float A = ((lane & 1) ? b1 : b0) + v01;
        float u23 = (lane & 1) ? b2 : b3;
        float v23 = __shfl_xor(u23, 1);
        float B = ((lane & 1) ? b3 : b2) + v23;
        float uu = (lane & 2) ? A : B;
        float vv = __shfl_xor(uu, 2);
        float S = ((lane & 2) ? B : A) + vv;
        #pragma unroll
        for (int s = 4; s < 64; s <<= 1) S += __shfl_xor(S, s);
        if (lane < 4) part[k][w][lane] = S;
    }
    __syncthreads();
    // bwd flush: slot = block % 8 (disjoint rows per i0 within a slot)
    {
        const int k = threadIdx.x >> 2, r = threadIdx.x & 3;
        const float s = (part[k][0][r] + part[k][1][r]) + (part[k][2][r] + part[k][3][r]);
        bwdp[(size_t)(blockIdx.x & 7) * (NN * 4) + (size_t)(i0 + (k << 7)) * 4 + r] = s;
    }
    // fwd flush: per-i0 slot, coalesced float4s
    float4* fp = (float4*)fwdp + (size_t)i0 * NN + col;
    fp[0] = acc0; fp[1] = acc1; fp[2] = acc2; fp[3] = acc3;
}

// ---- reduce 128 fwd + 8 bwd slots + combine (512 blocks, 4-wave slot split) ----
__global__ __launch_bounds__(256) void k_final6(
    const float* __restrict__ fwdp, const float* __restrict__ bwdp,
    const float* __restrict__ rc, const float* __restrict__ modes,
    float* __restrict__ out) {
    __shared__ float fs[4][64], bs[4][64];
    const int lane = threadIdx.x & 63;
    const int w = threadIdx.x >> 6;
    const int o = blockIdx.x * 64 + lane;    // grid 512 -> 32768
    float f = 0.f;
    #pragma unroll
    for (int k = 0; k < 32; ++k) f += fwdp[(size_t)(w * 32 + k) * (NN * 4) + o];
    float b = 0.f;
    #pragma unroll
    for (int k = 0; k < 2; ++k) b += bwdp[(size_t)(w * 2 + k) * (NN * 4) + o];
    fs[w][lane] = f; bs[w][lane] = b;
    __syncthreads();
    if (threadIdx.x < 64) {
        const float F = (fs[0][lane] + fs[1][lane]) + (fs[2][lane] + fs[3][lane]);
        const float B = (bs[0][lane] + bs[1][lane]) + (bs[2][lane] + bs[3][lane]);
        const int r = o & 3;
        out[o] = B * modes[r * 3] + rc[o] * modes[r * 3 + 1] + F * modes[r * 3 + 2];
    }
}

// ==== fallback (round-4, proven) k_link + k_final ====
__global__ __launch_bounds__(256, 4) void k_link(
    const float* __restrict__ link, const float* __restrict__ ww,
    const float* __restrict__ prec, const float* __restrict__ rw,
    float* __restrict__ nl_out, float* __restrict__ fwd, float* __restrict__ bwd)
{
    __shared__ float part[64][16][4];
    __shared__ float fl[4][256][4];
    const int lane = threadIdx.x & 63;
    const int w = threadIdx.x >> 6;
    const int j = blockIdx.x * 256 + lane * 4;
    const float4 wwj = *(const float4*)&ww[j];
    const float4 pj  = *(const float4*)&prec[j];
    const float4 rwj0 = *(const float4*)&rw[j * 4];
    const float4 rwj1 = *(const float4*)&rw[j * 4 + 4];
    const float4 rwj2 = *(const float4*)&rw[j * 4 + 8];
    const float4 rwj3 = *(const float4*)&rw[j * 4 + 12];
    float fa[4][4];
    #pragma unroll
    for (int a = 0; a < 4; a++)
        #pragma unroll
        for (int r = 0; r < 4; r++) fa[a][r] = 0.f;
    for (int sub = 0; sub < 4; ++sub) {
        const int i00 = blockIdx.y * 256 + sub * 64;
        const int irow0 = i00 + w * 16;
        #pragma unroll 4
        for (int t = 0; t < 16; ++t) {
            const int i = irow0 + t;
            const float wwi = ww[i];
            const float4 rwi = *(const float4*)&rw[i * 4];
            const size_t off = (size_t)i * NN + j;
            const float4 Lv = *(const float4*)&link[off];
            const float c0 = 1.f - wwi;
            float4 e;
            e.x = (c0 - wwj.x) * Lv.x + wwi * pj.x;
            e.y = (c0 - wwj.y) * Lv.y + wwi * pj.y;
            e.z = (c0 - wwj.z) * Lv.z + wwi * pj.z;
            e.w = (c0 - wwj.w) * Lv.w + wwi * pj.w;
            *(float4*)&nl_out[off] = e;
            fa[0][0] += e.x * rwi.x; fa[0][1] += e.x * rwi.y; fa[0][2] += e.x * rwi.z; fa[0][3] += e.x * rwi.w;
            fa[1][0] += e.y * rwi.x; fa[1][1] += e.y * rwi.y; fa[1][2] += e.y * rwi.z; fa[1][3] += e.y * rwi.w;
            fa[2][0] += e.z * rwi.x; fa[2][1] += e.z * rwi.y; fa[2][2] += e.z * rwi.z; fa[2][3] += e.z * rwi.w;
            fa[3][0] += e.w * rwi.x; fa[3][1] += e.w * rwi.y; fa[3][2] += e.w * rwi.z; fa[3][3] += e.w * rwi.w;
            float b0 = e.x * rwj0.x + e.y * rwj1.x + e.z * rwj2.x + e.w * rwj3.x;
            float b1 = e.x * rwj0.y + e.y * rwj1.y + e.z * rwj2.y + e.w * rwj3.y;
            float b2 = e.x * rwj0.z + e.y * rwj1.z + e.z * rwj2.z + e.w * rwj3.z;
            float b3 = e.x * rwj0.w + e.y * rwj1.w + e.z * rwj2.w + e.w * rwj3.w;
            float u01 = (lane & 1) ? b0 : b1;
            float v01 = __shfl_xor(u01, 1);
            float A = ((lane & 1) ? b1 : b0) + v01;
            float u23 = (lane & 1) ? b2 : b3;
            float v23 = __shfl_xor(u23, 1);
            float B = ((lane & 1) ? b3 : b2) + v23;
            float uu = (lane & 2) ? A : B;
            float vv = __shfl_xor(uu, 2);
            float S = ((lane & 2) ? B : A) + vv;
            #pragma unroll
            for (int s = 4; s < 64; s <<= 1) S += __shfl_xor(S, s);
            const int row = w * 16 + t;
            if (lane < 4) part[row][((lane >> 2) + row) & 15][lane & 3] = S;
        }
        __syncthreads();
        if (threadIdx.x < 64) {
            const int row = threadIdx.x;
            float4 acc; acc.x = 0.f; acc.y = 0.f; acc.z = 0.f; acc.w = 0.f;
            #pragma unroll
            for (int k = 0; k < 16; ++k) {
                const float4 p = *(const float4*)&part[row][(k + row) & 15][0];
                acc.x += p.x; acc.y += p.y; acc.z += p.z; acc.w += p.w;
            }
            const int i = i00 + row;
            atomicAdd(&bwd[i * 4 + 0], acc.x);
            atomicAdd(&bwd[i * 4 + 1], acc.y);
            atomicAdd(&bwd[i * 4 + 2], acc.z);
            atomicAdd(&bwd[i * 4 + 3], acc.w);
        }
        __syncthreads();
    }
    #pragma unroll
    for (int a = 0; a < 4; a++)
        #pragma unroll
        for (int r = 0; r < 4; r++)
            fl[w][lane * 4 + a][r] = fa[a][r];
    __syncthreads();
    const int col = threadIdx.x;
    const float4 s0 = *(const float4*)&fl[0][col][0];
    const float4 s1 = *(const float4*)&fl[1][col][0];
    const float4 s2 = *(const float4*)&fl[2][col][0];
    const float4 s3 = *(const float4*)&fl[3][col][0];
    atomicAdd(&fwd[(blockIdx.x * 256 + col) * 4 + 0], s0.x + s1.x + s2.x + s3.x);
    atomicAdd(&fwd[(blockIdx.x * 256 + col) * 4 + 1], s0.y + s1.y + s2.y + s3.y);
    atomicAdd(&fwd[(blockIdx.x * 256 + col) * 4 + 2], s0.z + s1.z + s2.z + s3.z);
    atomicAdd(&fwd[(blockIdx.x * 256 + col) * 4 + 3], s0.w + s1.w + s2.w + s3.w);
}

__global__ void k_final(const float* __restrict__ fwd, const float* __restrict__ bwd,
                        const float* __restrict__ rc, const float* __restrict__ modes,
                        float* __restrict__ out) {
    int idx = blockIdx.x * 256 + threadIdx.x;
    int r = idx & 3;
    float m0 = modes[r * 3], m1 = modes[r * 3 + 1], m2 = modes[r * 3 + 2];
    out[idx] = bwd[idx] * m0 + rc[idx] * m1 + fwd[idx] * m2;
}

extern "C" void kernel_launch(void* const* d_in, const int* in_sizes, int n_in,
                              void* d_out, int out_size, void* d_ws, size_t ws_size,
                              hipStream_t stream) {
    const float* mem   = (const float*)d_in[0];
    const float* u     = (const float*)d_in[1];
    const float* prec  = (const float*)d_in[2];
    const float* link  = (const float*)d_in[3];
    const float* rw    = (const float*)d_in[4];
    const float* rk    = (const float*)d_in[5];
    const float* rstr  = (const float*)d_in[6];
    const float* wk    = (const float*)d_in[7];
    const float* wstr  = (const float*)d_in[8];
    const float* er    = (const float*)d_in[9];
    const float* wv    = (const float*)d_in[10];
    const float* fg    = (const float*)d_in[11];
    const float* ag    = (const float*)d_in[12];
    const float* wg    = (const float*)d_in[13];
    const float* modes = (const float*)d_in[14];
    float* out = (float*)d_out;
    float* ws  = (float*)d_ws;
    float* nlr = out + O_NL;

    k_zero<<<1, 64, 0, stream>>>(ws + S_SCAL);
    k_rowstats<<<256, 256, 0, stream>>>(mem, rw, wk, fg, wstr,
                                        nlr + P_RVP, ws + S_LOGITS, ws + S_RET, ws + S_SCAL);
    k_apart<<<512, 256, 0, stream>>>(u, nlr + P_APART, nlr + P_CPART, ws + S_FWD);
    k_grank<<<32, 256, 0, stream>>>(u, nlr + P_APART, nlr + P_CPART, nlr + P_RVP,
                                    ws + S_G, (int*)(ws + S_RANK), ws + S_SCAL, out + O_RV);
    k_scatter<<<32, 256, 0, stream>>>(ws + S_G, (const int*)(ws + S_RANK), ws + S_ALLOC);
    k_rownew<<<512, 256, 0, stream>>>(mem, ws + S_LOGITS, ws + S_ALLOC, u, ws + S_RET,
                                      prec, er, wv, rk, rstr, ag, wg, ws + S_SCAL,
                                      ws + S_WW, out + O_NM, out + O_NU, out + O_NP, ws + S_RC);

    if (ws_size >= WS_NEED2) {
        k_link6<<<1024, 256, 0, stream>>>(link, ws + S_WW, prec, rw, out + O_NL,
                                          ws + S_FWDP2, ws + S_BWDP2);
        k_final6<<<512, 256, 0, stream>>>(ws + S_FWDP2, ws + S_BWDP2, ws + S_RC, modes, out + O_NR);
    } else {
        dim3 lg(32, 32);
        k_link<<<lg, 256, 0, stream>>>(link, ws + S_WW, prec, rw, out + O_NL,
                                       ws + S_FWD, ws + S_BWD);
        k_final<<<128, 256, 0, stream>>>(ws + S_FWD, ws + S_BWD, ws + S_RC, modes, out + O_NR);
    }
}

// Round 13
// 172.231 us; speedup vs baseline: 1.5774x; 1.0541x over previous
//
#include <hip/hip_runtime.h>

#define NN 8192
#define WW_ 128
#define EPSF 1e-8f

typedef float vfloat4 __attribute__((ext_vector_type(4)));

// ws float offsets
#define S_LOGITS 0
#define S_ALLOC  8192
#define S_WW     16384
#define S_RET    24576
#define S_G      32768
#define S_RANK   40960
#define S_RC     49152      // 8192*4 -> ends 81920
#define S_SCAL   81920      // 32 scalars
#define S_FWD    90112      // fallback 8192*4
#define S_BWD    122880     // fallback 8192*4
#define S_BWDP2  163840     // 8 slots * 32768 (1 MB) -> ends 425984
#define S_FWDP2  524288     // 128 slots * 32768 (16 MB) -> ends 4718592
#define WS_NEED2 ((size_t)4718592 * 4)   // 18.87 MB (proven available)

// output float offsets
#define O_RV 0
#define O_NM 512
#define O_NU 1049088
#define O_NP 1057280
#define O_NL 1065472
#define O_NR 68174336

// scratch carved out of the (not-yet-written) new_link output region
#define P_APART 0           // 16*8192
#define P_CPART 131072      // 16*8192
#define P_RVP   262144      // 256*512 rv partials

__global__ void k_zero(float* __restrict__ scal) {
    if (threadIdx.x < 32) scal[threadIdx.x] = 0.f;
}

// ---- per-row: content logits, retention, read_vectors partials (no atomics) ----
__global__ __launch_bounds__(256, 4) void k_rowstats(
    const float* __restrict__ mem, const float* __restrict__ rw,
    const float* __restrict__ wk, const float* __restrict__ fg,
    const float* __restrict__ wstr,
    float* __restrict__ rvp, float* __restrict__ logits, float* __restrict__ ret,
    float* __restrict__ scal)
{
    __shared__ float sb[4][512];
    int lane = threadIdx.x & 63;
    int w = threadIdx.x >> 6;
    int wave = (blockIdx.x << 2) + w;            // 0..1023
    int c = lane * 2;
    float2 wk2 = *(const float2*)&wk[c];
    float4 fg4 = *(const float4*)&fg[0];
    float ws = wstr[0];
    float nw = wk2.x * wk2.x + wk2.y * wk2.y;
    #pragma unroll
    for (int s = 1; s < 64; s <<= 1) nw += __shfl_xor(nw, s);
    float wkn = sqrtf(nw);

    float arv[2][4];
    #pragma unroll
    for (int a = 0; a < 2; a++)
        #pragma unroll
        for (int r = 0; r < 4; r++) arv[a][r] = 0.f;
    float se = 0.f;
    int i0 = wave * 8;
    for (int t = 0; t < 8; t++) {
        int i = i0 + t;
        float2 m2 = *(const float2*)&mem[i * WW_ + c];
        float4 rwi = *(const float4*)&rw[i * 4];
        float dp = m2.x * wk2.x + m2.y * wk2.y;
        float nq = m2.x * m2.x + m2.y * m2.y;
        #pragma unroll
        for (int s = 1; s < 64; s <<= 1) { dp += __shfl_xor(dp, s); nq += __shfl_xor(nq, s); }
        arv[0][0] += m2.x * rwi.x; arv[0][1] += m2.x * rwi.y; arv[0][2] += m2.x * rwi.z; arv[0][3] += m2.x * rwi.w;
        arv[1][0] += m2.y * rwi.x; arv[1][1] += m2.y * rwi.y; arv[1][2] += m2.y * rwi.z; arv[1][3] += m2.y * rwi.w;
        if (lane == 0) {
            float denom = fmaxf(sqrtf(nq) * wkn, EPSF);
            float lg = dp / denom * ws;
            logits[i] = lg;
            ret[i] = (1.f - rwi.x * fg4.x) * (1.f - rwi.y * fg4.y) *
                     (1.f - rwi.z * fg4.z) * (1.f - rwi.w * fg4.w);
            se += __expf(lg);
        }
    }
    if (lane == 0) atomicAdd(&scal[6], se);
    #pragma unroll
    for (int a = 0; a < 2; a++)
        #pragma unroll
        for (int r = 0; r < 4; r++)
            sb[w][(c + a) * 4 + r] = arv[a][r];
    __syncthreads();
    for (int idx = threadIdx.x; idx < 512; idx += 256)
        rvp[blockIdx.x * 512 + idx] = sb[0][idx] + sb[1][idx] + sb[2][idx] + sb[3][idx];
}

// ---- allocation partials; also zeroes fallback fwd/bwd ----
__global__ __launch_bounds__(256) void k_apart(const float* __restrict__ u,
                                               float* __restrict__ apart,
                                               float* __restrict__ cpart,
                                               float* __restrict__ fbzero) {
    __shared__ float su[512];
    int gtid = blockIdx.x * 256 + threadIdx.x;
    if (gtid < 65536) fbzero[gtid] = 0.f;
    int jc = blockIdx.x >> 5;
    int ib = blockIdx.x & 31;
    int t = threadIdx.x;
    for (int q = t; q < 512; q += 256) su[q] = u[jc * 512 + q];
    __syncthreads();
    int i = ib * 256 + t;
    float ui = u[i];
    float p0 = 1.f, p1 = 1.f, p2 = 1.f, p3 = 1.f;
    int c0 = 0, c1 = 0, c2 = 0, c3 = 0;
    int jbase = jc * 512;
    for (int q = 0; q < 512; q += 4) {
        float a0 = su[q], a1 = su[q + 1], a2 = su[q + 2], a3 = su[q + 3];
        int j0 = jbase + q;
        bool m0 = (a0 < ui) || (a0 == ui && j0     < i);
        bool m1 = (a1 < ui) || (a1 == ui && j0 + 1 < i);
        bool m2 = (a2 < ui) || (a2 == ui && j0 + 2 < i);
        bool m3 = (a3 < ui) || (a3 == ui && j0 + 3 < i);
        p0 *= m0 ? a0 : 1.f; c0 += m0;
        p1 *= m1 ? a1 : 1.f; c1 += m1;
        p2 *= m2 ? a2 : 1.f; c2 += m2;
        p3 *= m3 ? a3 : 1.f; c3 += m3;
    }
    apart[jc * NN + i] = (p0 * p1) * (p2 * p3);
    cpart[jc * NN + i] = (float)((c0 + c1) + (c2 + c3));
}

// ---- combine partials -> g[i], rank[i], sum(g); blocks 0,1 also reduce rv ----
__global__ __launch_bounds__(256) void k_grank(
    const float* __restrict__ u, const float* __restrict__ apart,
    const float* __restrict__ cpart, const float* __restrict__ rvp,
    float* __restrict__ g, int* __restrict__ rank,
    float* __restrict__ scal, float* __restrict__ rv_out) {
    __shared__ float sb[256];
    int i = blockIdx.x * 256 + threadIdx.x;
    float p = 1.f, c = 0.f;
    #pragma unroll
    for (int jc = 0; jc < 16; jc++) { p *= apart[jc * NN + i]; c += cpart[jc * NN + i]; }
    float gi = (1.f - u[i]) * p;
    g[i] = gi;
    rank[i] = (int)c;
    sb[threadIdx.x] = gi; __syncthreads();
    for (int s = 128; s > 0; s >>= 1) { if (threadIdx.x < s) sb[threadIdx.x] += sb[threadIdx.x + s]; __syncthreads(); }
    if (threadIdx.x == 0) atomicAdd(&scal[8], sb[0]);
    if (blockIdx.x < 2) {
        int idx = blockIdx.x * 256 + threadIdx.x;
        float acc = 0.f;
        for (int pb = 0; pb < 256; pb++) acc += rvp[pb * 512 + idx];
        rv_out[idx] = acc;
    }
}

// ---- reference's alloc_sorted[order] gather == out[rank[rank[m]]] = g[m] ----
__global__ void k_scatter(const float* __restrict__ g, const int* __restrict__ rank,
                          float* __restrict__ alloc) {
    int m = blockIdx.x * 256 + threadIdx.x;
    alloc[rank[rank[m]]] = g[m];
}

// ---- per-row epilogue ----
__global__ __launch_bounds__(256, 4) void k_rownew(
    const float* __restrict__ mem, const float* __restrict__ logits,
    const float* __restrict__ alloc, const float* __restrict__ u,
    const float* __restrict__ ret, const float* __restrict__ prec,
    const float* __restrict__ er, const float* __restrict__ wv,
    const float* __restrict__ rk, const float* __restrict__ rstr,
    const float* __restrict__ ag, const float* __restrict__ wg_,
    const float* __restrict__ scal,
    float* __restrict__ ww_out, float* __restrict__ nm_out,
    float* __restrict__ nu_out, float* __restrict__ np_out, float* __restrict__ rc_out)
{
    int lane = threadIdx.x & 63;
    int wave = (blockIdx.x << 2) + (threadIdx.x >> 6);
    int c = lane * 2;
    float2 er2 = *(const float2*)&er[c];
    float2 wv2 = *(const float2*)&wv[c];
    float4 rka = *(const float4*)&rk[c * 4];
    float4 rkb = *(const float4*)&rk[(c + 1) * 4];
    float4 rs4 = *(const float4*)&rstr[0];
    float n0 = rka.x * rka.x + rkb.x * rkb.x;
    float n1 = rka.y * rka.y + rkb.y * rkb.y;
    float n2 = rka.z * rka.z + rkb.z * rkb.z;
    float n3 = rka.w * rka.w + rkb.w * rkb.w;
    #pragma unroll
    for (int s = 1; s < 64; s <<= 1) {
        n0 += __shfl_xor(n0, s); n1 += __shfl_xor(n1, s);
        n2 += __shfl_xor(n2, s); n3 += __shfl_xor(n3, s);
    }
    float rkn0 = sqrtf(n0), rkn1 = sqrtf(n1), rkn2 = sqrtf(n2), rkn3 = sqrtf(n3);
    float invS = 1.f / scal[6];
    float Sg = scal[8];
    float ga = ag[0], wg = wg_[0];
    float wsum = wg * (ga * Sg + (1.f - ga));
    int i0 = wave * 4;
    for (int t = 0; t < 4; t++) {
        int i = i0 + t;
        float wwi = wg * (ga * alloc[i] + (1.f - ga) * __expf(logits[i]) * invS);
        float2 m2 = *(const float2*)&mem[i * WW_ + c];
        float nx = m2.x * (1.f - wwi * er2.x) + wwi * wv2.x;
        float ny = m2.y * (1.f - wwi * er2.y) + wwi * wv2.y;
        float2 nm2; nm2.x = nx; nm2.y = ny;
        *(float2*)&nm_out[i * WW_ + c] = nm2;
        float nq = nx * nx + ny * ny;
        float d0 = nx * rka.x + ny * rkb.x;
        float d1 = nx * rka.y + ny * rkb.y;
        float d2 = nx * rka.z + ny * rkb.z;
        float d3 = nx * rka.w + ny * rkb.w;
        #pragma unroll
        for (int s = 1; s < 64; s <<= 1) {
            nq += __shfl_xor(nq, s);
            d0 += __shfl_xor(d0, s); d1 += __shfl_xor(d1, s);
            d2 += __shfl_xor(d2, s); d3 += __shfl_xor(d3, s);
        }
        if (lane == 0) {
            float nrm = sqrtf(nq);
            float l0 = d0 / (nrm * rkn0) * rs4.x;
            float l1 = d1 / (nrm * rkn1) * rs4.y;
            float l2 = d2 / (nrm * rkn2) * rs4.z;
            float l3 = d3 / (nrm * rkn3) * rs4.w;
            float m4 = fmaxf(fmaxf(l0, l1), fmaxf(l2, l3));
            float e0 = __expf(l0 - m4), e1 = __expf(l1 - m4);
            float e2 = __expf(l2 - m4), e3 = __expf(l3 - m4);
            float si = 1.f / (e0 + e1 + e2 + e3);
            float4 rc; rc.x = e0 * si; rc.y = e1 * si; rc.z = e2 * si; rc.w = e3 * si;
            *(float4*)&rc_out[i * 4] = rc;
            ww_out[i] = wwi;
            float ui = u[i];
            nu_out[i] = (ui + wwi - ui * wwi) * ret[i];
            np_out[i] = (1.f - wsum) * prec[i] + wwi;
        }
    }
}

// ==== fused k_link6: sequential sweep, NT LOADS (bypass L3 for read-once link),
//      cached stores (write set stays L3-resident), scalarized row loads ====
__global__ __launch_bounds__(256, 4) void k_link6(
    const float* __restrict__ link, const float* __restrict__ ww,
    const float* __restrict__ prec, const float* __restrict__ rw,
    float* __restrict__ nl_out, float* __restrict__ fwdp, float* __restrict__ bwdp)
{
    __shared__ float part[64][4][4];       // 4 KB
    const int lane = threadIdx.x & 63;
    const int w = threadIdx.x >> 6;
    const int tid = blockIdx.x * 256 + threadIdx.x;    // 0..262143
    const int j4 = tid & 2047;                          // vec4 column
    const int i0 = __builtin_amdgcn_readfirstlane(tid >> 11);   // 0..127, wave-uniform
    const int col = j4 * 4;
    const vfloat4* L4 = (const vfloat4*)link;
    const float4* RW4 = (const float4*)rw;
    float4* NL4 = (float4*)nl_out;

    const float4 wwj = *(const float4*)&ww[col];
    const float4 pj  = *(const float4*)&prec[col];
    const float4 rj0 = RW4[col + 0];
    const float4 rj1 = RW4[col + 1];
    const float4 rj2 = RW4[col + 2];
    const float4 rj3 = RW4[col + 3];
    float4 rwT0, rwT1, rwT2, rwT3;          // rwT[r][c] = rw[col_c][r]
    rwT0.x = rj0.x; rwT0.y = rj1.x; rwT0.z = rj2.x; rwT0.w = rj3.x;
    rwT1.x = rj0.y; rwT1.y = rj1.y; rwT1.z = rj2.y; rwT1.w = rj3.y;
    rwT2.x = rj0.z; rwT2.y = rj1.z; rwT2.z = rj2.z; rwT2.w = rj3.z;
    rwT3.x = rj0.w; rwT3.y = rj1.w; rwT3.z = rj2.w; rwT3.w = rj3.w;

    float4 acc0, acc1, acc2, acc3;
    acc0.x = acc0.y = acc0.z = acc0.w = 0.f;
    acc1 = acc0; acc2 = acc0; acc3 = acc0;

    #pragma unroll 8
    for (int k = 0; k < 64; ++k) {
        const int i = i0 + (k << 7);                    // wave-uniform -> scalar loads
        const float wwi = ww[i];
        const float4 rwi = RW4[i];
        const size_t v = (size_t)tid + ((size_t)k << 18);
        const vfloat4 Lv = __builtin_nontemporal_load(L4 + v);   // stream past L3
        const float cc = 1.f - wwi;
        float4 e;
        e.x = (cc - wwj.x) * Lv.x + wwi * pj.x;
        e.y = (cc - wwj.y) * Lv.y + wwi * pj.y;
        e.z = (cc - wwj.z) * Lv.z + wwi * pj.z;
        e.w = (cc - wwj.w) * Lv.w + wwi * pj.w;
        NL4[v] = e;                                     // cached store (L3-retained)
        acc0.x += e.x * rwi.x; acc0.y += e.x * rwi.y; acc0.z += e.x * rwi.z; acc0.w += e.x * rwi.w;
        acc1.x += e.y * rwi.x; acc1.y += e.y * rwi.y; acc1.z += e.y * rwi.z; acc1.w += e.y * rwi.w;
        acc2.x += e.z * rwi.x; acc2.y += e.z * rwi.y; acc2.z += e.z * rwi.z; acc2.w += e.z * rwi.w;
        acc3.x += e.w * rwi.x; acc3.y += e.w * rwi.y; acc3.z += e.w * rwi.z; acc3.w += e.w * rwi.w;
        // bwd: 7-shuffle wave reduce of this row's 256-col slice
        float b0 = e.x * rwT0.x + e.y * rwT0.y + e.z * rwT0.z + e.w * rwT0.w;
        float b1 = e.x * rwT1.x + e.y * rwT1.y + e.z * rwT1.z + e.w * rwT1.w;
        float b2 = e.x * rwT2.x + e.y * rwT2.y + e.z * rwT2.z + e.w * rwT2.w;
        float b3 = e.x * rwT3.x + e.y * rwT3.y + e.z * rwT3.z + e.w * rwT3.w;
        float u01 = (lane & 1) ? b0 : b1;
        float v01 = __shfl_xor(u01, 1);
        float A = ((lane & 1) ? b1 : b0) + v01;
        float u23 = (lane & 1) ? b2 : b3;
        float v23 = __shfl_xor(u23, 1);
        float B = ((lane & 1) ? b3 : b2) + v23;
        float uu = (lane & 2) ? A : B;
        float vv = __shfl_xor(uu, 2);
        float S = ((lane & 2) ? B : A) + vv;
        #pragma unroll
        for (int s = 4; s < 64; s <<= 1) S += __shfl_xor(S, s);
        if (lane < 4) part[k][w][lane] = S;
    }
    __syncthreads();
    // bwd flush: slot = block % 8 (disjoint rows per i0 within a slot)
    {
        const int k = threadIdx.x >> 2, r = threadIdx.x & 3;
        const float s = (part[k][0][r] + part[k][1][r]) + (part[k][2][r] + part[k][3][r]);
        bwdp[(size_t)(blockIdx.x & 7) * (NN * 4) + (size_t)(i0 + (k << 7)) * 4 + r] = s;
    }
    // fwd flush: per-i0 slot, coalesced float4s
    float4* fp = (float4*)fwdp + (size_t)i0 * NN + col;
    fp[0] = acc0; fp[1] = acc1; fp[2] = acc2; fp[3] = acc3;
}

// ---- reduce 128 fwd + 8 bwd slots + combine (512 blocks, 4-wave slot split) ----
__global__ __launch_bounds__(256) void k_final6(
    const float* __restrict__ fwdp, const float* __restrict__ bwdp,
    const float* __restrict__ rc, const float* __restrict__ modes,
    float* __restrict__ out) {
    __shared__ float fs[4][64], bs[4][64];
    const int lane = threadIdx.x & 63;
    const int w = threadIdx.x >> 6;
    const int o = blockIdx.x * 64 + lane;    // grid 512 -> 32768
    float f = 0.f;
    #pragma unroll
    for (int k = 0; k < 32; ++k) f += fwdp[(size_t)(w * 32 + k) * (NN * 4) + o];
    float b = 0.f;
    #pragma unroll
    for (int k = 0; k < 2; ++k) b += bwdp[(size_t)(w * 2 + k) * (NN * 4) + o];
    fs[w][lane] = f; bs[w][lane] = b;
    __syncthreads();
    if (threadIdx.x < 64) {
        const float F = (fs[0][lane] + fs[1][lane]) + (fs[2][lane] + fs[3][lane]);
        const float B = (bs[0][lane] + bs[1][lane]) + (bs[2][lane] + bs[3][lane]);
        const int r = o & 3;
        out[o] = B * modes[r * 3] + rc[o] * modes[r * 3 + 1] + F * modes[r * 3 + 2];
    }
}

// ==== fallback (round-4, proven) k_link + k_final ====
__global__ __launch_bounds__(256, 4) void k_link(
    const float* __restrict__ link, const float* __restrict__ ww,
    const float* __restrict__ prec, const float* __restrict__ rw,
    float* __restrict__ nl_out, float* __restrict__ fwd, float* __restrict__ bwd)
{
    __shared__ float part[64][16][4];
    __shared__ float fl[4][256][4];
    const int lane = threadIdx.x & 63;
    const int w = threadIdx.x >> 6;
    const int j = blockIdx.x * 256 + lane * 4;
    const float4 wwj = *(const float4*)&ww[j];
    const float4 pj  = *(const float4*)&prec[j];
    const float4 rwj0 = *(const float4*)&rw[j * 4];
    const float4 rwj1 = *(const float4*)&rw[j * 4 + 4];
    const float4 rwj2 = *(const float4*)&rw[j * 4 + 8];
    const float4 rwj3 = *(const float4*)&rw[j * 4 + 12];
    float fa[4][4];
    #pragma unroll
    for (int a = 0; a < 4; a++)
        #pragma unroll
        for (int r = 0; r < 4; r++) fa[a][r] = 0.f;
    for (int sub = 0; sub < 4; ++sub) {
        const int i00 = blockIdx.y * 256 + sub * 64;
        const int irow0 = i00 + w * 16;
        #pragma unroll 4
        for (int t = 0; t < 16; ++t) {
            const int i = irow0 + t;
            const float wwi = ww[i];
            const float4 rwi = *(const float4*)&rw[i * 4];
            const size_t off = (size_t)i * NN + j;
            const float4 Lv = *(const float4*)&link[off];
            const float c0 = 1.f - wwi;
            float4 e;
            e.x = (c0 - wwj.x) * Lv.x + wwi * pj.x;
            e.y = (c0 - wwj.y) * Lv.y + wwi * pj.y;
            e.z = (c0 - wwj.z) * Lv.z + wwi * pj.z;
            e.w = (c0 - wwj.w) * Lv.w + wwi * pj.w;
            *(float4*)&nl_out[off] = e;
            fa[0][0] += e.x * rwi.x; fa[0][1] += e.x * rwi.y; fa[0][2] += e.x * rwi.z; fa[0][3] += e.x * rwi.w;
            fa[1][0] += e.y * rwi.x; fa[1][1] += e.y * rwi.y; fa[1][2] += e.y * rwi.z; fa[1][3] += e.y * rwi.w;
            fa[2][0] += e.z * rwi.x; fa[2][1] += e.z * rwi.y; fa[2][2] += e.z * rwi.z; fa[2][3] += e.z * rwi.w;
            fa[3][0] += e.w * rwi.x; fa[3][1] += e.w * rwi.y; fa[3][2] += e.w * rwi.z; fa[3][3] += e.w * rwi.w;
            float b0 = e.x * rwj0.x + e.y * rwj1.x + e.z * rwj2.x + e.w * rwj3.x;
            float b1 = e.x * rwj0.y + e.y * rwj1.y + e.z * rwj2.y + e.w * rwj3.y;
            float b2 = e.x * rwj0.z + e.y * rwj1.z + e.z * rwj2.z + e.w * rwj3.z;
            float b3 = e.x * rwj0.w + e.y * rwj1.w + e.z * rwj2.w + e.w * rwj3.w;
            float u01 = (lane & 1) ? b0 : b1;
            float v01 = __shfl_xor(u01, 1);
            float A = ((lane & 1) ? b1 : b0) + v01;
            float u23 = (lane & 1) ? b2 : b3;
            float v23 = __shfl_xor(u23, 1);
            float B = ((lane & 1) ? b3 : b2) + v23;
            float uu = (lane & 2) ? A : B;
            float vv = __shfl_xor(uu, 2);
            float S = ((lane & 2) ? B : A) + vv;
            #pragma unroll
            for (int s = 4; s < 64; s <<= 1) S += __shfl_xor(S, s);
            const int row = w * 16 + t;
            if (lane < 4) part[row][((lane >> 2) + row) & 15][lane & 3] = S;
        }
        __syncthreads();
        if (threadIdx.x < 64) {
            const int row = threadIdx.x;
            float4 acc; acc.x = 0.f; acc.y = 0.f; acc.z = 0.f; acc.w = 0.f;
            #pragma unroll
            for (int k = 0; k < 16; ++k) {
                const float4 p = *(const float4*)&part[row][(k + row) & 15][0];
                acc.x += p.x; acc.y += p.y; acc.z += p.z; acc.w += p.w;
            }
            const int i = i00 + row;
            atomicAdd(&bwd[i * 4 + 0], acc.x);
            atomicAdd(&bwd[i * 4 + 1], acc.y);
            atomicAdd(&bwd[i * 4 + 2], acc.z);
            atomicAdd(&bwd[i * 4 + 3], acc.w);
        }
        __syncthreads();
    }
    #pragma unroll
    for (int a = 0; a < 4; a++)
        #pragma unroll
        for (int r = 0; r < 4; r++)
            fl[w][lane * 4 + a][r] = fa[a][r];
    __syncthreads();
    const int col = threadIdx.x;
    const float4 s0 = *(const float4*)&fl[0][col][0];
    const float4 s1 = *(const float4*)&fl[1][col][0];
    const float4 s2 = *(const float4*)&fl[2][col][0];
    const float4 s3 = *(const float4*)&fl[3][col][0];
    atomicAdd(&fwd[(blockIdx.x * 256 + col) * 4 + 0], s0.x + s1.x + s2.x + s3.x);
    atomicAdd(&fwd[(blockIdx.x * 256 + col) * 4 + 1], s0.y + s1.y + s2.y + s3.y);
    atomicAdd(&fwd[(blockIdx.x * 256 + col) * 4 + 2], s0.z + s1.z + s2.z + s3.z);
    atomicAdd(&fwd[(blockIdx.x * 256 + col) * 4 + 3], s0.w + s1.w + s2.w + s3.w);
}

__global__ void k_final(const float* __restrict__ fwd, const float* __restrict__ bwd,
                        const float* __restrict__ rc, const float* __restrict__ modes,
                        float* __restrict__ out) {
    int idx = blockIdx.x * 256 + threadIdx.x;
    int r = idx & 3;
    float m0 = modes[r * 3], m1 = modes[r * 3 + 1], m2 = modes[r * 3 + 2];
    out[idx] = bwd[idx] * m0 + rc[idx] * m1 + fwd[idx] * m2;
}

extern "C" void kernel_launch(void* const* d_in, const int* in_sizes, int n_in,
                              void* d_out, int out_size, void* d_ws, size_t ws_size,
                              hipStream_t stream) {
    const float* mem   = (const float*)d_in[0];
    const float* u     = (const float*)d_in[1];
    const float* prec  = (const float*)d_in[2];
    const float* link  = (const float*)d_in[3];
    const float* rw    = (const float*)d_in[4];
    const float* rk    = (const float*)d_in[5];
    const float* rstr  = (const float*)d_in[6];
    const float* wk    = (const float*)d_in[7];
    const float* wstr  = (const float*)d_in[8];
    const float* er    = (const float*)d_in[9];
    const float* wv    = (const float*)d_in[10];
    const float* fg    = (const float*)d_in[11];
    const float* ag    = (const float*)d_in[12];
    const float* wg    = (const float*)d_in[13];
    const float* modes = (const float*)d_in[14];
    float* out = (float*)d_out;
    float* ws  = (float*)d_ws;
    float* nlr = out + O_NL;

    k_zero<<<1, 64, 0, stream>>>(ws + S_SCAL);
    k_rowstats<<<256, 256, 0, stream>>>(mem, rw, wk, fg, wstr,
                                        nlr + P_RVP, ws + S_LOGITS, ws + S_RET, ws + S_SCAL);
    k_apart<<<512, 256, 0, stream>>>(u, nlr + P_APART, nlr + P_CPART, ws + S_FWD);
    k_grank<<<32, 256, 0, stream>>>(u, nlr + P_APART, nlr + P_CPART, nlr + P_RVP,
                                    ws + S_G, (int*)(ws + S_RANK), ws + S_SCAL, out + O_RV);
    k_scatter<<<32, 256, 0, stream>>>(ws + S_G, (const int*)(ws + S_RANK), ws + S_ALLOC);
    k_rownew<<<512, 256, 0, stream>>>(mem, ws + S_LOGITS, ws + S_ALLOC, u, ws + S_RET,
                                      prec, er, wv, rk, rstr, ag, wg, ws + S_SCAL,
                                      ws + S_WW, out + O_NM, out + O_NU, out + O_NP, ws + S_RC);

    if (ws_size >= WS_NEED2) {
        k_link6<<<1024, 256, 0, stream>>>(link, ws + S_WW, prec, rw, out + O_NL,
                                          ws + S_FWDP2, ws + S_BWDP2);
        k_final6<<<512, 256, 0, stream>>>(ws + S_FWDP2, ws + S_BWDP2, ws + S_RC, modes, out + O_NR);
    } else {
        dim3 lg(32, 32);
        k_link<<<lg, 256, 0, stream>>>(link, ws + S_WW, prec, rw, out + O_NL,
                                       ws + S_FWD, ws + S_BWD);
        k_final<<<128, 256, 0, stream>>>(ws + S_FWD, ws + S_BWD, ws + S_RC, modes, out + O_NR);
    }
}

// Round 14
// 149.955 us; speedup vs baseline: 1.8117x; 1.1486x over previous
//
#include <hip/hip_runtime.h>

#define NN 8192
#define WW_ 128
#define EPSF 1e-8f

typedef float vfloat4 __attribute__((ext_vector_type(4)));

// ws float offsets
#define S_LOGITS 0
#define S_ALLOC  8192
#define S_WW     16384
#define S_RET    24576
#define S_G      32768
#define S_RANK   40960
#define S_RC     49152      // 8192*4 -> ends 81920
#define S_SCAL   81920      // 32 scalars: [6]=sum exp, [8]=sum g
#define S_FWD    90112      // fallback 8192*4
#define S_BWD    122880     // fallback 8192*4
#define S_BWDP2  163840     // 8 slots * 32768 (1 MB) -> ends 425984
#define S_FWDP2  524288     // 128 slots * 32768 (16 MB) -> ends 4718592
#define WS_NEED2 ((size_t)4718592 * 4)   // 18.87 MB (proven available)

// output float offsets
#define O_RV 0
#define O_NM 512
#define O_NU 1049088
#define O_NP 1057280
#define O_NL 1065472
#define O_NR 68174336

// scratch carved out of the (not-yet-written) new_link output region
#define P_APART 0           // 16*8192
#define P_CPART 131072      // 16*8192
#define P_RVP   262144      // 256*512 rv partials -> ends 393216
#define P_SE    393216      // 256 per-block sum-exp partials
#define P_GS    393472      // 32 per-block g-sum partials

// ---- fused: blocks 0..255 rowstats, blocks 256..767 alloc partials ----
__global__ __launch_bounds__(256, 4) void k_stats_apart(
    const float* __restrict__ mem, const float* __restrict__ rw,
    const float* __restrict__ wk, const float* __restrict__ fg,
    const float* __restrict__ wstr, const float* __restrict__ u,
    float* __restrict__ rvp, float* __restrict__ logits, float* __restrict__ ret,
    float* __restrict__ separt, float* __restrict__ apart, float* __restrict__ cpart)
{
    __shared__ float sb[4][512];
    __shared__ float seb[4];
    if (blockIdx.x < 256) {
        int lane = threadIdx.x & 63;
        int w = threadIdx.x >> 6;
        int wave = (blockIdx.x << 2) + w;            // 0..1023
        int c = lane * 2;
        float2 wk2 = *(const float2*)&wk[c];
        float4 fg4 = *(const float4*)&fg[0];
        float ws = wstr[0];
        float nw = wk2.x * wk2.x + wk2.y * wk2.y;
        #pragma unroll
        for (int s = 1; s < 64; s <<= 1) nw += __shfl_xor(nw, s);
        float wkn = sqrtf(nw);

        float arv[2][4];
        #pragma unroll
        for (int a = 0; a < 2; a++)
            #pragma unroll
            for (int r = 0; r < 4; r++) arv[a][r] = 0.f;
        float se = 0.f;
        int i0 = wave * 8;
        for (int t = 0; t < 8; t++) {
            int i = i0 + t;
            float2 m2 = *(const float2*)&mem[i * WW_ + c];
            float4 rwi = *(const float4*)&rw[i * 4];
            float dp = m2.x * wk2.x + m2.y * wk2.y;
            float nq = m2.x * m2.x + m2.y * m2.y;
            #pragma unroll
            for (int s = 1; s < 64; s <<= 1) { dp += __shfl_xor(dp, s); nq += __shfl_xor(nq, s); }
            arv[0][0] += m2.x * rwi.x; arv[0][1] += m2.x * rwi.y; arv[0][2] += m2.x * rwi.z; arv[0][3] += m2.x * rwi.w;
            arv[1][0] += m2.y * rwi.x; arv[1][1] += m2.y * rwi.y; arv[1][2] += m2.y * rwi.z; arv[1][3] += m2.y * rwi.w;
            if (lane == 0) {
                float denom = fmaxf(sqrtf(nq) * wkn, EPSF);
                float lg = dp / denom * ws;
                logits[i] = lg;
                ret[i] = (1.f - rwi.x * fg4.x) * (1.f - rwi.y * fg4.y) *
                         (1.f - rwi.z * fg4.z) * (1.f - rwi.w * fg4.w);
                se += __expf(lg);
            }
        }
        if (lane == 0) seb[w] = se;
        #pragma unroll
        for (int a = 0; a < 2; a++)
            #pragma unroll
            for (int r = 0; r < 4; r++)
                sb[w][(c + a) * 4 + r] = arv[a][r];
        __syncthreads();
        for (int idx = threadIdx.x; idx < 512; idx += 256)
            rvp[blockIdx.x * 512 + idx] = sb[0][idx] + sb[1][idx] + sb[2][idx] + sb[3][idx];
        if (threadIdx.x == 0)
            separt[blockIdx.x] = (seb[0] + seb[1]) + (seb[2] + seb[3]);
    } else {
        float* su = &sb[0][0];                   // reuse LDS (512 floats)
        int b2 = blockIdx.x - 256;               // 0..511
        int jc = b2 >> 5;                        // 0..15
        int ib = b2 & 31;
        int t = threadIdx.x;
        for (int q = t; q < 512; q += 256) su[q] = u[jc * 512 + q];
        __syncthreads();
        int i = ib * 256 + t;
        float ui = u[i];
        float p0 = 1.f, p1 = 1.f, p2 = 1.f, p3 = 1.f;
        int c0 = 0, c1 = 0, c2 = 0, c3 = 0;
        int jbase = jc * 512;
        for (int q = 0; q < 512; q += 4) {
            float a0 = su[q], a1 = su[q + 1], a2 = su[q + 2], a3 = su[q + 3];
            int j0 = jbase + q;
            bool m0 = (a0 < ui) || (a0 == ui && j0     < i);
            bool m1 = (a1 < ui) || (a1 == ui && j0 + 1 < i);
            bool m2 = (a2 < ui) || (a2 == ui && j0 + 2 < i);
            bool m3 = (a3 < ui) || (a3 == ui && j0 + 3 < i);
            p0 *= m0 ? a0 : 1.f; c0 += m0;
            p1 *= m1 ? a1 : 1.f; c1 += m1;
            p2 *= m2 ? a2 : 1.f; c2 += m2;
            p3 *= m3 ? a3 : 1.f; c3 += m3;
        }
        apart[jc * NN + i] = (p0 * p1) * (p2 * p3);
        cpart[jc * NN + i] = (float)((c0 + c1) + (c2 + c3));
    }
}

// ---- combine partials -> g[i], rank[i]; per-block g-sum (no atomics);
//      blocks 0,1 reduce rv; block 2 reduces sum-exp -> scal[6] ----
__global__ __launch_bounds__(256) void k_grank(
    const float* __restrict__ u, const float* __restrict__ apart,
    const float* __restrict__ cpart, const float* __restrict__ rvp,
    const float* __restrict__ separt,
    float* __restrict__ g, int* __restrict__ rank,
    float* __restrict__ gpart, float* __restrict__ scal, float* __restrict__ rv_out) {
    __shared__ float sb[256];
    int i = blockIdx.x * 256 + threadIdx.x;
    float p = 1.f, c = 0.f;
    #pragma unroll
    for (int jc = 0; jc < 16; jc++) { p *= apart[jc * NN + i]; c += cpart[jc * NN + i]; }
    float gi = (1.f - u[i]) * p;
    g[i] = gi;
    rank[i] = (int)c;
    sb[threadIdx.x] = gi; __syncthreads();
    for (int s = 128; s > 0; s >>= 1) { if (threadIdx.x < s) sb[threadIdx.x] += sb[threadIdx.x + s]; __syncthreads(); }
    if (threadIdx.x == 0) gpart[blockIdx.x] = sb[0];
    if (blockIdx.x < 2) {
        int idx = blockIdx.x * 256 + threadIdx.x;
        float acc = 0.f;
        for (int pb = 0; pb < 256; pb++) acc += rvp[pb * 512 + idx];
        rv_out[idx] = acc;
    } else if (blockIdx.x == 2) {
        __syncthreads();
        sb[threadIdx.x] = separt[threadIdx.x]; __syncthreads();
        for (int s = 128; s > 0; s >>= 1) { if (threadIdx.x < s) sb[threadIdx.x] += sb[threadIdx.x + s]; __syncthreads(); }
        if (threadIdx.x == 0) scal[6] = sb[0];
    }
}

// ---- scatter alloc (out[rank[rank[m]]] = g[m]); block 0 reduces g-sum -> scal[8] ----
__global__ void k_scatter(const float* __restrict__ g, const int* __restrict__ rank,
                          const float* __restrict__ gpart,
                          float* __restrict__ alloc, float* __restrict__ scal) {
    int m = blockIdx.x * 256 + threadIdx.x;
    alloc[rank[rank[m]]] = g[m];
    if (blockIdx.x == 0 && threadIdx.x < 32) {
        float v = gpart[threadIdx.x];
        #pragma unroll
        for (int s = 1; s < 32; s <<= 1) v += __shfl_xor(v, s);
        if (threadIdx.x == 0) scal[8] = v;
    }
}

// ---- per-row epilogue ----
__global__ __launch_bounds__(256, 4) void k_rownew(
    const float* __restrict__ mem, const float* __restrict__ logits,
    const float* __restrict__ alloc, const float* __restrict__ u,
    const float* __restrict__ ret, const float* __restrict__ prec,
    const float* __restrict__ er, const float* __restrict__ wv,
    const float* __restrict__ rk, const float* __restrict__ rstr,
    const float* __restrict__ ag, const float* __restrict__ wg_,
    const float* __restrict__ scal,
    float* __restrict__ ww_out, float* __restrict__ nm_out,
    float* __restrict__ nu_out, float* __restrict__ np_out, float* __restrict__ rc_out)
{
    int lane = threadIdx.x & 63;
    int wave = (blockIdx.x << 2) + (threadIdx.x >> 6);
    int c = lane * 2;
    float2 er2 = *(const float2*)&er[c];
    float2 wv2 = *(const float2*)&wv[c];
    float4 rka = *(const float4*)&rk[c * 4];
    float4 rkb = *(const float4*)&rk[(c + 1) * 4];
    float4 rs4 = *(const float4*)&rstr[0];
    float n0 = rka.x * rka.x + rkb.x * rkb.x;
    float n1 = rka.y * rka.y + rkb.y * rkb.y;
    float n2 = rka.z * rka.z + rkb.z * rkb.z;
    float n3 = rka.w * rka.w + rkb.w * rkb.w;
    #pragma unroll
    for (int s = 1; s < 64; s <<= 1) {
        n0 += __shfl_xor(n0, s); n1 += __shfl_xor(n1, s);
        n2 += __shfl_xor(n2, s); n3 += __shfl_xor(n3, s);
    }
    float rkn0 = sqrtf(n0), rkn1 = sqrtf(n1), rkn2 = sqrtf(n2), rkn3 = sqrtf(n3);
    float invS = 1.f / scal[6];
    float Sg = scal[8];
    float ga = ag[0], wg = wg_[0];
    float wsum = wg * (ga * Sg + (1.f - ga));
    int i0 = wave * 4;
    for (int t = 0; t < 4; t++) {
        int i = i0 + t;
        float wwi = wg * (ga * alloc[i] + (1.f - ga) * __expf(logits[i]) * invS);
        float2 m2 = *(const float2*)&mem[i * WW_ + c];
        float nx = m2.x * (1.f - wwi * er2.x) + wwi * wv2.x;
        float ny = m2.y * (1.f - wwi * er2.y) + wwi * wv2.y;
        float2 nm2; nm2.x = nx; nm2.y = ny;
        *(float2*)&nm_out[i * WW_ + c] = nm2;
        float nq = nx * nx + ny * ny;
        float d0 = nx * rka.x + ny * rkb.x;
        float d1 = nx * rka.y + ny * rkb.y;
        float d2 = nx * rka.z + ny * rkb.z;
        float d3 = nx * rka.w + ny * rkb.w;
        #pragma unroll
        for (int s = 1; s < 64; s <<= 1) {
            nq += __shfl_xor(nq, s);
            d0 += __shfl_xor(d0, s); d1 += __shfl_xor(d1, s);
            d2 += __shfl_xor(d2, s); d3 += __shfl_xor(d3, s);
        }
        if (lane == 0) {
            float nrm = sqrtf(nq);
            float l0 = d0 / (nrm * rkn0) * rs4.x;
            float l1 = d1 / (nrm * rkn1) * rs4.y;
            float l2 = d2 / (nrm * rkn2) * rs4.z;
            float l3 = d3 / (nrm * rkn3) * rs4.w;
            float m4 = fmaxf(fmaxf(l0, l1), fmaxf(l2, l3));
            float e0 = __expf(l0 - m4), e1 = __expf(l1 - m4);
            float e2 = __expf(l2 - m4), e3 = __expf(l3 - m4);
            float si = 1.f / (e0 + e1 + e2 + e3);
            float4 rc; rc.x = e0 * si; rc.y = e1 * si; rc.z = e2 * si; rc.w = e3 * si;
            *(float4*)&rc_out[i * 4] = rc;
            ww_out[i] = wwi;
            float ui = u[i];
            nu_out[i] = (ui + wwi - ui * wwi) * ret[i];
            np_out[i] = (1.f - wsum) * prec[i] + wwi;
        }
    }
}

// ==== fused k_link6 (r13-proven): NT loads, cached stores, scalarized row loads ====
__global__ __launch_bounds__(256, 4) void k_link6(
    const float* __restrict__ link, const float* __restrict__ ww,
    const float* __restrict__ prec, const float* __restrict__ rw,
    float* __restrict__ nl_out, float* __restrict__ fwdp, float* __restrict__ bwdp)
{
    __shared__ float part[64][4][4];       // 4 KB
    const int lane = threadIdx.x & 63;
    const int w = threadIdx.x >> 6;
    const int tid = blockIdx.x * 256 + threadIdx.x;    // 0..262143
    const int j4 = tid & 2047;                          // vec4 column
    const int i0 = __builtin_amdgcn_readfirstlane(tid >> 11);   // 0..127, wave-uniform
    const int col = j4 * 4;
    const vfloat4* L4 = (const vfloat4*)link;
    const float4* RW4 = (const float4*)rw;
    float4* NL4 = (float4*)nl_out;

    const float4 wwj = *(const float4*)&ww[col];
    const float4 pj  = *(const float4*)&prec[col];
    const float4 rj0 = RW4[col + 0];
    const float4 rj1 = RW4[col + 1];
    const float4 rj2 = RW4[col + 2];
    const float4 rj3 = RW4[col + 3];
    float4 rwT0, rwT1, rwT2, rwT3;          // rwT[r][c] = rw[col_c][r]
    rwT0.x = rj0.x; rwT0.y = rj1.x; rwT0.z = rj2.x; rwT0.w = rj3.x;
    rwT1.x = rj0.y; rwT1.y = rj1.y; rwT1.z = rj2.y; rwT1.w = rj3.y;
    rwT2.x = rj0.z; rwT2.y = rj1.z; rwT2.z = rj2.z; rwT2.w = rj3.z;
    rwT3.x = rj0.w; rwT3.y = rj1.w; rwT3.z = rj2.w; rwT3.w = rj3.w;

    float4 acc0, acc1, acc2, acc3;
    acc0.x = acc0.y = acc0.z = acc0.w = 0.f;
    acc1 = acc0; acc2 = acc0; acc3 = acc0;

    #pragma unroll 8
    for (int k = 0; k < 64; ++k) {
        const int i = i0 + (k << 7);                    // wave-uniform -> scalar loads
        const float wwi = ww[i];
        const float4 rwi = RW4[i];
        const size_t v = (size_t)tid + ((size_t)k << 18);
        const vfloat4 Lv = __builtin_nontemporal_load(L4 + v);   // stream past L3
        const float cc = 1.f - wwi;
        float4 e;
        e.x = (cc - wwj.x) * Lv.x + wwi * pj.x;
        e.y = (cc - wwj.y) * Lv.y + wwi * pj.y;
        e.z = (cc - wwj.z) * Lv.z + wwi * pj.z;
        e.w = (cc - wwj.w) * Lv.w + wwi * pj.w;
        NL4[v] = e;                                     // cached store (L3-retained)
        acc0.x += e.x * rwi.x; acc0.y += e.x * rwi.y; acc0.z += e.x * rwi.z; acc0.w += e.x * rwi.w;
        acc1.x += e.y * rwi.x; acc1.y += e.y * rwi.y; acc1.z += e.y * rwi.z; acc1.w += e.y * rwi.w;
        acc2.x += e.z * rwi.x; acc2.y += e.z * rwi.y; acc2.z += e.z * rwi.z; acc2.w += e.z * rwi.w;
        acc3.x += e.w * rwi.x; acc3.y += e.w * rwi.y; acc3.z += e.w * rwi.z; acc3.w += e.w * rwi.w;
        float b0 = e.x * rwT0.x + e.y * rwT0.y + e.z * rwT0.z + e.w * rwT0.w;
        float b1 = e.x * rwT1.x + e.y * rwT1.y + e.z * rwT1.z + e.w * rwT1.w;
        float b2 = e.x * rwT2.x + e.y * rwT2.y + e.z * rwT2.z + e.w * rwT2.w;
        float b3 = e.x * rwT3.x + e.y * rwT3.y + e.z * rwT3.z + e.w * rwT3.w;
        float u01 = (lane & 1) ? b0 : b1;
        float v01 = __shfl_xor(u01, 1);
        float A = ((lane & 1) ? b1 : b0) + v01;
        float u23 = (lane & 1) ? b2 : b3;
        float v23 = __shfl_xor(u23, 1);
        float B = ((lane & 1) ? b3 : b2) + v23;
        float uu = (lane & 2) ? A : B;
        float vv = __shfl_xor(uu, 2);
        float S = ((lane & 2) ? B : A) + vv;
        #pragma unroll
        for (int s = 4; s < 64; s <<= 1) S += __shfl_xor(S, s);
        if (lane < 4) part[k][w][lane] = S;
    }
    __syncthreads();
    {
        const int k = threadIdx.x >> 2, r = threadIdx.x & 3;
        const float s = (part[k][0][r] + part[k][1][r]) + (part[k][2][r] + part[k][3][r]);
        bwdp[(size_t)(blockIdx.x & 7) * (NN * 4) + (size_t)(i0 + (k << 7)) * 4 + r] = s;
    }
    float4* fp = (float4*)fwdp + (size_t)i0 * NN + col;
    fp[0] = acc0; fp[1] = acc1; fp[2] = acc2; fp[3] = acc3;
}

// ---- reduce 128 fwd + 8 bwd slots + combine ----
__global__ __launch_bounds__(256) void k_final6(
    const float* __restrict__ fwdp, const float* __restrict__ bwdp,
    const float* __restrict__ rc, const float* __restrict__ modes,
    float* __restrict__ out) {
    __shared__ float fs[4][64], bs[4][64];
    const int lane = threadIdx.x & 63;
    const int w = threadIdx.x >> 6;
    const int o = blockIdx.x * 64 + lane;    // grid 512 -> 32768
    float f = 0.f;
    #pragma unroll
    for (int k = 0; k < 32; ++k) f += fwdp[(size_t)(w * 32 + k) * (NN * 4) + o];
    float b = 0.f;
    #pragma unroll
    for (int k = 0; k < 2; ++k) b += bwdp[(size_t)(w * 2 + k) * (NN * 4) + o];
    fs[w][lane] = f; bs[w][lane] = b;
    __syncthreads();
    if (threadIdx.x < 64) {
        const float F = (fs[0][lane] + fs[1][lane]) + (fs[2][lane] + fs[3][lane]);
        const float B = (bs[0][lane] + bs[1][lane]) + (bs[2][lane] + bs[3][lane]);
        const int r = o & 3;
        out[o] = B * modes[r * 3] + rc[o] * modes[r * 3 + 1] + F * modes[r * 3 + 2];
    }
}

// ==== fallback path (only if ws too small): zero + r4-proven fused k_link ====
__global__ void k_zero_fb(float* __restrict__ p, int n) {
    int i = blockIdx.x * 256 + threadIdx.x;
    if (i < n) p[i] = 0.f;
}

__global__ __launch_bounds__(256, 4) void k_link(
    const float* __restrict__ link, const float* __restrict__ ww,
    const float* __restrict__ prec, const float* __restrict__ rw,
    float* __restrict__ nl_out, float* __restrict__ fwd, float* __restrict__ bwd)
{
    __shared__ float part[64][16][4];
    __shared__ float fl[4][256][4];
    const int lane = threadIdx.x & 63;
    const int w = threadIdx.x >> 6;
    const int j = blockIdx.x * 256 + lane * 4;
    const float4 wwj = *(const float4*)&ww[j];
    const float4 pj  = *(const float4*)&prec[j];
    const float4 rwj0 = *(const float4*)&rw[j * 4];
    const float4 rwj1 = *(const float4*)&rw[j * 4 + 4];
    const float4 rwj2 = *(const float4*)&rw[j * 4 + 8];
    const float4 rwj3 = *(const float4*)&rw[j * 4 + 12];
    float fa[4][4];
    #pragma unroll
    for (int a = 0; a < 4; a++)
        #pragma unroll
        for (int r = 0; r < 4; r++) fa[a][r] = 0.f;
    for (int sub = 0; sub < 4; ++sub) {
        const int i00 = blockIdx.y * 256 + sub * 64;
        const int irow0 = i00 + w * 16;
        #pragma unroll 4
        for (int t = 0; t < 16; ++t) {
            const int i = irow0 + t;
            const float wwi = ww[i];
            const float4 rwi = *(const float4*)&rw[i * 4];
            const size_t off = (size_t)i * NN + j;
            const float4 Lv = *(const float4*)&link[off];
            const float c0 = 1.f - wwi;
            float4 e;
            e.x = (c0 - wwj.x) * Lv.x + wwi * pj.x;
            e.y = (c0 - wwj.y) * Lv.y + wwi * pj.y;
            e.z = (c0 - wwj.z) * Lv.z + wwi * pj.z;
            e.w = (c0 - wwj.w) * Lv.w + wwi * pj.w;
            *(float4*)&nl_out[off] = e;
            fa[0][0] += e.x * rwi.x; fa[0][1] += e.x * rwi.y; fa[0][2] += e.x * rwi.z; fa[0][3] += e.x * rwi.w;
            fa[1][0] += e.y * rwi.x; fa[1][1] += e.y * rwi.y; fa[1][2] += e.y * rwi.z; fa[1][3] += e.y * rwi.w;
            fa[2][0] += e.z * rwi.x; fa[2][1] += e.z * rwi.y; fa[2][2] += e.z * rwi.z; fa[2][3] += e.z * rwi.w;
            fa[3][0] += e.w * rwi.x; fa[3][1] += e.w * rwi.y; fa[3][2] += e.w * rwi.z; fa[3][3] += e.w * rwi.w;
            float b0 = e.x * rwj0.x + e.y * rwj1.x + e.z * rwj2.x + e.w * rwj3.x;
            float b1 = e.x * rwj0.y + e.y * rwj1.y + e.z * rwj2.y + e.w * rwj3.y;
            float b2 = e.x * rwj0.z + e.y * rwj1.z + e.z * rwj2.z + e.w * rwj3.z;
            float b3 = e.x * rwj0.w + e.y * rwj1.w + e.z * rwj2.w + e.w * rwj3.w;
            float u01 = (lane & 1) ? b0 : b1;
            float v01 = __shfl_xor(u01, 1);
            float A = ((lane & 1) ? b1 : b0) + v01;
            float u23 = (lane & 1) ? b2 : b3;
            float v23 = __shfl_xor(u23, 1);
            float B = ((lane & 1) ? b3 : b2) + v23;
            float uu = (lane & 2) ? A : B;
            float vv = __shfl_xor(uu, 2);
            float S = ((lane & 2) ? B : A) + vv;
            #pragma unroll
            for (int s = 4; s < 64; s <<= 1) S += __shfl_xor(S, s);
            const int row = w * 16 + t;
            if (lane < 4) part[row][((lane >> 2) + row) & 15][lane & 3] = S;
        }
        __syncthreads();
        if (threadIdx.x < 64) {
            const int row = threadIdx.x;
            float4 acc; acc.x = 0.f; acc.y = 0.f; acc.z = 0.f; acc.w = 0.f;
            #pragma unroll
            for (int k = 0; k < 16; ++k) {
                const float4 p = *(const float4*)&part[row][(k + row) & 15][0];
                acc.x += p.x; acc.y += p.y; acc.z += p.z; acc.w += p.w;
            }
            const int i = i00 + row;
            atomicAdd(&bwd[i * 4 + 0], acc.x);
            atomicAdd(&bwd[i * 4 + 1], acc.y);
            atomicAdd(&bwd[i * 4 + 2], acc.z);
            atomicAdd(&bwd[i * 4 + 3], acc.w);
        }
        __syncthreads();
    }
    #pragma unroll
    for (int a = 0; a < 4; a++)
        #pragma unroll
        for (int r = 0; r < 4; r++)
            fl[w][lane * 4 + a][r] = fa[a][r];
    __syncthreads();
    const int col = threadIdx.x;
    const float4 s0 = *(const float4*)&fl[0][col][0];
    const float4 s1 = *(const float4*)&fl[1][col][0];
    const float4 s2 = *(const float4*)&fl[2][col][0];
    const float4 s3 = *(const float4*)&fl[3][col][0];
    atomicAdd(&fwd[(blockIdx.x * 256 + col) * 4 + 0], s0.x + s1.x + s2.x + s3.x);
    atomicAdd(&fwd[(blockIdx.x * 256 + col) * 4 + 1], s0.y + s1.y + s2.y + s3.y);
    atomicAdd(&fwd[(blockIdx.x * 256 + col) * 4 + 2], s0.z + s1.z + s2.z + s3.z);
    atomicAdd(&fwd[(blockIdx.x * 256 + col) * 4 + 3], s0.w + s1.w + s2.w + s3.w);
}

__global__ void k_final(const float* __restrict__ fwd, const float* __restrict__ bwd,
                        const float* __restrict__ rc, const float* __restrict__ modes,
                        float* __restrict__ out) {
    int idx = blockIdx.x * 256 + threadIdx.x;
    int r = idx & 3;
    float m0 = modes[r * 3], m1 = modes[r * 3 + 1], m2 = modes[r * 3 + 2];
    out[idx] = bwd[idx] * m0 + rc[idx] * m1 + fwd[idx] * m2;
}

extern "C" void kernel_launch(void* const* d_in, const int* in_sizes, int n_in,
                              void* d_out, int out_size, void* d_ws, size_t ws_size,
                              hipStream_t stream) {
    const float* mem   = (const float*)d_in[0];
    const float* u     = (const float*)d_in[1];
    const float* prec  = (const float*)d_in[2];
    const float* link  = (const float*)d_in[3];
    const float* rw    = (const float*)d_in[4];
    const float* rk    = (const float*)d_in[5];
    const float* rstr  = (const float*)d_in[6];
    const float* wk    = (const float*)d_in[7];
    const float* wstr  = (const float*)d_in[8];
    const float* er    = (const float*)d_in[9];
    const float* wv    = (const float*)d_in[10];
    const float* fg    = (const float*)d_in[11];
    const float* ag    = (const float*)d_in[12];
    const float* wg    = (const float*)d_in[13];
    const float* modes = (const float*)d_in[14];
    float* out = (float*)d_out;
    float* ws  = (float*)d_ws;
    float* nlr = out + O_NL;

    k_stats_apart<<<768, 256, 0, stream>>>(mem, rw, wk, fg, wstr, u,
                                           nlr + P_RVP, ws + S_LOGITS, ws + S_RET,
                                           nlr + P_SE, nlr + P_APART, nlr + P_CPART);
    k_grank<<<32, 256, 0, stream>>>(u, nlr + P_APART, nlr + P_CPART, nlr + P_RVP,
                                    nlr + P_SE, ws + S_G, (int*)(ws + S_RANK),
                                    nlr + P_GS, ws + S_SCAL, out + O_RV);
    k_scatter<<<32, 256, 0, stream>>>(ws + S_G, (const int*)(ws + S_RANK),
                                      nlr + P_GS, ws + S_ALLOC, ws + S_SCAL);
    k_rownew<<<512, 256, 0, stream>>>(mem, ws + S_LOGITS, ws + S_ALLOC, u, ws + S_RET,
                                      prec, er, wv, rk, rstr, ag, wg, ws + S_SCAL,
                                      ws + S_WW, out + O_NM, out + O_NU, out + O_NP, ws + S_RC);

    if (ws_size >= WS_NEED2) {
        k_link6<<<1024, 256, 0, stream>>>(link, ws + S_WW, prec, rw, out + O_NL,
                                          ws + S_FWDP2, ws + S_BWDP2);
        k_final6<<<512, 256, 0, stream>>>(ws + S_FWDP2, ws + S_BWDP2, ws + S_RC, modes, out + O_NR);
    } else {
        k_zero_fb<<<257, 256, 0, stream>>>(ws + S_FWD, 65568);
        dim3 lg(32, 32);
        k_link<<<lg, 256, 0, stream>>>(link, ws + S_WW, prec, rw, out + O_NL,
                                       ws + S_FWD, ws + S_BWD);
        k_final<<<128, 256, 0, stream>>>(ws + S_FWD, ws + S_BWD, ws + S_RC, modes, out + O_NR);
    }
}

// Round 15
// 149.740 us; speedup vs baseline: 1.8144x; 1.0014x over previous
//
#include <hip/hip_runtime.h>

#define NN 8192
#define WW_ 128
#define EPSF 1e-8f

typedef float vfloat4 __attribute__((ext_vector_type(4)));

// ws float offsets
#define S_LOGITS 0
#define S_ALLOC  8192
#define S_WW     16384
#define S_RET    24576
#define S_G      32768
#define S_RANK   40960
#define S_RC     49152      // 8192*4 -> ends 81920
#define S_SCAL   81920      // 32 scalars: [6]=sum exp, [8]=sum g
#define S_FWD    90112      // fallback 8192*4
#define S_BWD    122880     // fallback 8192*4
#define S_BWDP2  163840     // 8 slots * 32768 (1 MB) -> ends 425984
#define S_FWDP2  524288     // 128 slots * 32768 (16 MB) -> ends 4718592
#define WS_NEED2 ((size_t)4718592 * 4)   // 18.87 MB (proven available)

// output float offsets
#define O_RV 0
#define O_NM 512
#define O_NU 1049088
#define O_NP 1057280
#define O_NL 1065472
#define O_NR 68174336

// scratch carved out of the (not-yet-written) new_link output region
#define P_APART 0           // 16*8192
#define P_CPART 131072      // 16*8192
#define P_RVP   262144      // 256*512 rv partials -> ends 393216
#define P_SE    393216      // 256 per-block sum-exp partials
#define P_GS    393472      // 32 per-block g-sum partials

// ---- fused: blocks 0..255 rowstats, blocks 256..767 alloc partials ----
__global__ __launch_bounds__(256, 4) void k_stats_apart(
    const float* __restrict__ mem, const float* __restrict__ rw,
    const float* __restrict__ wk, const float* __restrict__ fg,
    const float* __restrict__ wstr, const float* __restrict__ u,
    float* __restrict__ rvp, float* __restrict__ logits, float* __restrict__ ret,
    float* __restrict__ separt, float* __restrict__ apart, float* __restrict__ cpart)
{
    __shared__ float sb[4][512];
    __shared__ float seb[4];
    if (blockIdx.x < 256) {
        int lane = threadIdx.x & 63;
        int w = threadIdx.x >> 6;
        int wave = (blockIdx.x << 2) + w;            // 0..1023
        int c = lane * 2;
        float2 wk2 = *(const float2*)&wk[c];
        float4 fg4 = *(const float4*)&fg[0];
        float ws = wstr[0];
        float nw = wk2.x * wk2.x + wk2.y * wk2.y;
        #pragma unroll
        for (int s = 1; s < 64; s <<= 1) nw += __shfl_xor(nw, s);
        float wkn = sqrtf(nw);

        float arv[2][4];
        #pragma unroll
        for (int a = 0; a < 2; a++)
            #pragma unroll
            for (int r = 0; r < 4; r++) arv[a][r] = 0.f;
        float se = 0.f;
        int i0 = wave * 8;
        for (int t = 0; t < 8; t++) {
            int i = i0 + t;
            float2 m2 = *(const float2*)&mem[i * WW_ + c];
            float4 rwi = *(const float4*)&rw[i * 4];
            float dp = m2.x * wk2.x + m2.y * wk2.y;
            float nq = m2.x * m2.x + m2.y * m2.y;
            #pragma unroll
            for (int s = 1; s < 64; s <<= 1) { dp += __shfl_xor(dp, s); nq += __shfl_xor(nq, s); }
            arv[0][0] += m2.x * rwi.x; arv[0][1] += m2.x * rwi.y; arv[0][2] += m2.x * rwi.z; arv[0][3] += m2.x * rwi.w;
            arv[1][0] += m2.y * rwi.x; arv[1][1] += m2.y * rwi.y; arv[1][2] += m2.y * rwi.z; arv[1][3] += m2.y * rwi.w;
            if (lane == 0) {
                float denom = fmaxf(sqrtf(nq) * wkn, EPSF);
                float lg = dp / denom * ws;
                logits[i] = lg;
                ret[i] = (1.f - rwi.x * fg4.x) * (1.f - rwi.y * fg4.y) *
                         (1.f - rwi.z * fg4.z) * (1.f - rwi.w * fg4.w);
                se += __expf(lg);
            }
        }
        if (lane == 0) seb[w] = se;
        #pragma unroll
        for (int a = 0; a < 2; a++)
            #pragma unroll
            for (int r = 0; r < 4; r++)
                sb[w][(c + a) * 4 + r] = arv[a][r];
        __syncthreads();
        for (int idx = threadIdx.x; idx < 512; idx += 256)
            rvp[blockIdx.x * 512 + idx] = sb[0][idx] + sb[1][idx] + sb[2][idx] + sb[3][idx];
        if (threadIdx.x == 0)
            separt[blockIdx.x] = (seb[0] + seb[1]) + (seb[2] + seb[3]);
    } else {
        float* su = &sb[0][0];                   // reuse LDS (512 floats)
        int b2 = blockIdx.x - 256;               // 0..511
        int jc = b2 >> 5;                        // 0..15
        int ib = b2 & 31;
        int t = threadIdx.x;
        for (int q = t; q < 512; q += 256) su[q] = u[jc * 512 + q];
        __syncthreads();
        int i = ib * 256 + t;
        float ui = u[i];
        float p0 = 1.f, p1 = 1.f, p2 = 1.f, p3 = 1.f;
        int c0 = 0, c1 = 0, c2 = 0, c3 = 0;
        int jbase = jc * 512;
        for (int q = 0; q < 512; q += 4) {
            float a0 = su[q], a1 = su[q + 1], a2 = su[q + 2], a3 = su[q + 3];
            int j0 = jbase + q;
            bool m0 = (a0 < ui) || (a0 == ui && j0     < i);
            bool m1 = (a1 < ui) || (a1 == ui && j0 + 1 < i);
            bool m2 = (a2 < ui) || (a2 == ui && j0 + 2 < i);
            bool m3 = (a3 < ui) || (a3 == ui && j0 + 3 < i);
            p0 *= m0 ? a0 : 1.f; c0 += m0;
            p1 *= m1 ? a1 : 1.f; c1 += m1;
            p2 *= m2 ? a2 : 1.f; c2 += m2;
            p3 *= m3 ? a3 : 1.f; c3 += m3;
        }
        apart[jc * NN + i] = (p0 * p1) * (p2 * p3);
        cpart[jc * NN + i] = (float)((c0 + c1) + (c2 + c3));
    }
}

// ---- combine partials -> g[i], rank[i]; per-block g-sum (no atomics);
//      blocks 0,1 reduce rv; block 2 reduces sum-exp -> scal[6] ----
__global__ __launch_bounds__(256) void k_grank(
    const float* __restrict__ u, const float* __restrict__ apart,
    const float* __restrict__ cpart, const float* __restrict__ rvp,
    const float* __restrict__ separt,
    float* __restrict__ g, int* __restrict__ rank,
    float* __restrict__ gpart, float* __restrict__ scal, float* __restrict__ rv_out) {
    __shared__ float sb[256];
    int i = blockIdx.x * 256 + threadIdx.x;
    float p = 1.f, c = 0.f;
    #pragma unroll
    for (int jc = 0; jc < 16; jc++) { p *= apart[jc * NN + i]; c += cpart[jc * NN + i]; }
    float gi = (1.f - u[i]) * p;
    g[i] = gi;
    rank[i] = (int)c;
    sb[threadIdx.x] = gi; __syncthreads();
    for (int s = 128; s > 0; s >>= 1) { if (threadIdx.x < s) sb[threadIdx.x] += sb[threadIdx.x + s]; __syncthreads(); }
    if (threadIdx.x == 0) gpart[blockIdx.x] = sb[0];
    if (blockIdx.x < 2) {
        int idx = blockIdx.x * 256 + threadIdx.x;
        float acc = 0.f;
        for (int pb = 0; pb < 256; pb++) acc += rvp[pb * 512 + idx];
        rv_out[idx] = acc;
    } else if (blockIdx.x == 2) {
        __syncthreads();
        sb[threadIdx.x] = separt[threadIdx.x]; __syncthreads();
        for (int s = 128; s > 0; s >>= 1) { if (threadIdx.x < s) sb[threadIdx.x] += sb[threadIdx.x + s]; __syncthreads(); }
        if (threadIdx.x == 0) scal[6] = sb[0];
    }
}

// ---- scatter alloc (out[rank[rank[m]]] = g[m]); block 0 reduces g-sum -> scal[8] ----
__global__ void k_scatter(const float* __restrict__ g, const int* __restrict__ rank,
                          const float* __restrict__ gpart,
                          float* __restrict__ alloc, float* __restrict__ scal) {
    int m = blockIdx.x * 256 + threadIdx.x;
    alloc[rank[rank[m]]] = g[m];
    if (blockIdx.x == 0 && threadIdx.x < 32) {
        float v = gpart[threadIdx.x];
        #pragma unroll
        for (int s = 1; s < 32; s <<= 1) v += __shfl_xor(v, s);
        if (threadIdx.x == 0) scal[8] = v;
    }
}

// ---- per-row epilogue ----
__global__ __launch_bounds__(256, 4) void k_rownew(
    const float* __restrict__ mem, const float* __restrict__ logits,
    const float* __restrict__ alloc, const float* __restrict__ u,
    const float* __restrict__ ret, const float* __restrict__ prec,
    const float* __restrict__ er, const float* __restrict__ wv,
    const float* __restrict__ rk, const float* __restrict__ rstr,
    const float* __restrict__ ag, const float* __restrict__ wg_,
    const float* __restrict__ scal,
    float* __restrict__ ww_out, float* __restrict__ nm_out,
    float* __restrict__ nu_out, float* __restrict__ np_out, float* __restrict__ rc_out)
{
    int lane = threadIdx.x & 63;
    int wave = (blockIdx.x << 2) + (threadIdx.x >> 6);
    int c = lane * 2;
    float2 er2 = *(const float2*)&er[c];
    float2 wv2 = *(const float2*)&wv[c];
    float4 rka = *(const float4*)&rk[c * 4];
    float4 rkb = *(const float4*)&rk[(c + 1) * 4];
    float4 rs4 = *(const float4*)&rstr[0];
    float n0 = rka.x * rka.x + rkb.x * rkb.x;
    float n1 = rka.y * rka.y + rkb.y * rkb.y;
    float n2 = rka.z * rka.z + rkb.z * rkb.z;
    float n3 = rka.w * rka.w + rkb.w * rkb.w;
    #pragma unroll
    for (int s = 1; s < 64; s <<= 1) {
        n0 += __shfl_xor(n0, s); n1 += __shfl_xor(n1, s);
        n2 += __shfl_xor(n2, s); n3 += __shfl_xor(n3, s);
    }
    float rkn0 = sqrtf(n0), rkn1 = sqrtf(n1), rkn2 = sqrtf(n2), rkn3 = sqrtf(n3);
    float invS = 1.f / scal[6];
    float Sg = scal[8];
    float ga = ag[0], wg = wg_[0];
    float wsum = wg * (ga * Sg + (1.f - ga));
    int i0 = wave * 4;
    for (int t = 0; t < 4; t++) {
        int i = i0 + t;
        float wwi = wg * (ga * alloc[i] + (1.f - ga) * __expf(logits[i]) * invS);
        float2 m2 = *(const float2*)&mem[i * WW_ + c];
        float nx = m2.x * (1.f - wwi * er2.x) + wwi * wv2.x;
        float ny = m2.y * (1.f - wwi * er2.y) + wwi * wv2.y;
        float2 nm2; nm2.x = nx; nm2.y = ny;
        *(float2*)&nm_out[i * WW_ + c] = nm2;
        float nq = nx * nx + ny * ny;
        float d0 = nx * rka.x + ny * rkb.x;
        float d1 = nx * rka.y + ny * rkb.y;
        float d2 = nx * rka.z + ny * rkb.z;
        float d3 = nx * rka.w + ny * rkb.w;
        #pragma unroll
        for (int s = 1; s < 64; s <<= 1) {
            nq += __shfl_xor(nq, s);
            d0 += __shfl_xor(d0, s); d1 += __shfl_xor(d1, s);
            d2 += __shfl_xor(d2, s); d3 += __shfl_xor(d3, s);
        }
        if (lane == 0) {
            float nrm = sqrtf(nq);
            float l0 = d0 / (nrm * rkn0) * rs4.x;
            float l1 = d1 / (nrm * rkn1) * rs4.y;
            float l2 = d2 / (nrm * rkn2) * rs4.z;
            float l3 = d3 / (nrm * rkn3) * rs4.w;
            float m4 = fmaxf(fmaxf(l0, l1), fmaxf(l2, l3));
            float e0 = __expf(l0 - m4), e1 = __expf(l1 - m4);
            float e2 = __expf(l2 - m4), e3 = __expf(l3 - m4);
            float si = 1.f / (e0 + e1 + e2 + e3);
            float4 rc; rc.x = e0 * si; rc.y = e1 * si; rc.z = e2 * si; rc.w = e3 * si;
            *(float4*)&rc_out[i * 4] = rc;
            ww_out[i] = wwi;
            float ui = u[i];
            nu_out[i] = (ui + wwi - ui * wwi) * ret[i];
            np_out[i] = (1.f - wsum) * prec[i] + wwi;
        }
    }
}

// ==== fused k_link6: NT loads AND NT stores (pure HBM stream), scalarized row loads ====
__global__ __launch_bounds__(256, 4) void k_link6(
    const float* __restrict__ link, const float* __restrict__ ww,
    const float* __restrict__ prec, const float* __restrict__ rw,
    float* __restrict__ nl_out, float* __restrict__ fwdp, float* __restrict__ bwdp)
{
    __shared__ float part[64][4][4];       // 4 KB
    const int lane = threadIdx.x & 63;
    const int w = threadIdx.x >> 6;
    const int tid = blockIdx.x * 256 + threadIdx.x;    // 0..262143
    const int j4 = tid & 2047;                          // vec4 column
    const int i0 = __builtin_amdgcn_readfirstlane(tid >> 11);   // 0..127, wave-uniform
    const int col = j4 * 4;
    const vfloat4* L4 = (const vfloat4*)link;
    const float4* RW4 = (const float4*)rw;
    vfloat4* NL4 = (vfloat4*)nl_out;

    const float4 wwj = *(const float4*)&ww[col];
    const float4 pj  = *(const float4*)&prec[col];
    const float4 rj0 = RW4[col + 0];
    const float4 rj1 = RW4[col + 1];
    const float4 rj2 = RW4[col + 2];
    const float4 rj3 = RW4[col + 3];
    float4 rwT0, rwT1, rwT2, rwT3;          // rwT[r][c] = rw[col_c][r]
    rwT0.x = rj0.x; rwT0.y = rj1.x; rwT0.z = rj2.x; rwT0.w = rj3.x;
    rwT1.x = rj0.y; rwT1.y = rj1.y; rwT1.z = rj2.y; rwT1.w = rj3.y;
    rwT2.x = rj0.z; rwT2.y = rj1.z; rwT2.z = rj2.z; rwT2.w = rj3.z;
    rwT3.x = rj0.w; rwT3.y = rj1.w; rwT3.z = rj2.w; rwT3.w = rj3.w;

    float4 acc0, acc1, acc2, acc3;
    acc0.x = acc0.y = acc0.z = acc0.w = 0.f;
    acc1 = acc0; acc2 = acc0; acc3 = acc0;

    #pragma unroll 8
    for (int k = 0; k < 64; ++k) {
        const int i = i0 + (k << 7);                    // wave-uniform -> scalar loads
        const float wwi = ww[i];
        const float4 rwi = RW4[i];
        const size_t v = (size_t)tid + ((size_t)k << 18);
        const vfloat4 Lv = __builtin_nontemporal_load(L4 + v);   // stream past L3
        const float cc = 1.f - wwi;
        float4 e;
        e.x = (cc - wwj.x) * Lv.x + wwi * pj.x;
        e.y = (cc - wwj.y) * Lv.y + wwi * pj.y;
        e.z = (cc - wwj.z) * Lv.z + wwi * pj.z;
        e.w = (cc - wwj.w) * Lv.w + wwi * pj.w;
        vfloat4 ev; ev.x = e.x; ev.y = e.y; ev.z = e.z; ev.w = e.w;
        __builtin_nontemporal_store(ev, NL4 + v);       // NT store: bypass L3 entirely
        acc0.x += e.x * rwi.x; acc0.y += e.x * rwi.y; acc0.z += e.x * rwi.z; acc0.w += e.x * rwi.w;
        acc1.x += e.y * rwi.x; acc1.y += e.y * rwi.y; acc1.z += e.y * rwi.z; acc1.w += e.y * rwi.w;
        acc2.x += e.z * rwi.x; acc2.y += e.z * rwi.y; acc2.z += e.z * rwi.z; acc2.w += e.z * rwi.w;
        acc3.x += e.w * rwi.x; acc3.y += e.w * rwi.y; acc3.z += e.w * rwi.z; acc3.w += e.w * rwi.w;
        float b0 = e.x * rwT0.x + e.y * rwT0.y + e.z * rwT0.z + e.w * rwT0.w;
        float b1 = e.x * rwT1.x + e.y * rwT1.y + e.z * rwT1.z + e.w * rwT1.w;
        float b2 = e.x * rwT2.x + e.y * rwT2.y + e.z * rwT2.z + e.w * rwT2.w;
        float b3 = e.x * rwT3.x + e.y * rwT3.y + e.z * rwT3.z + e.w * rwT3.w;
        float u01 = (lane & 1) ? b0 : b1;
        float v01 = __shfl_xor(u01, 1);
        float A = ((lane & 1) ? b1 : b0) + v01;
        float u23 = (lane & 1) ? b2 : b3;
        float v23 = __shfl_xor(u23, 1);
        float B = ((lane & 1) ? b3 : b2) + v23;
        float uu = (lane & 2) ? A : B;
        float vv = __shfl_xor(uu, 2);
        float S = ((lane & 2) ? B : A) + vv;
        #pragma unroll
        for (int s = 4; s < 64; s <<= 1) S += __shfl_xor(S, s);
        if (lane < 4) part[k][w][lane] = S;
    }
    __syncthreads();
    {
        const int k = threadIdx.x >> 2, r = threadIdx.x & 3;
        const float s = (part[k][0][r] + part[k][1][r]) + (part[k][2][r] + part[k][3][r]);
        bwdp[(size_t)(blockIdx.x & 7) * (NN * 4) + (size_t)(i0 + (k << 7)) * 4 + r] = s;
    }
    float4* fp = (float4*)fwdp + (size_t)i0 * NN + col;
    fp[0] = acc0; fp[1] = acc1; fp[2] = acc2; fp[3] = acc3;
}

// ---- reduce 128 fwd + 8 bwd slots + combine ----
__global__ __launch_bounds__(256) void k_final6(
    const float* __restrict__ fwdp, const float* __restrict__ bwdp,
    const float* __restrict__ rc, const float* __restrict__ modes,
    float* __restrict__ out) {
    __shared__ float fs[4][64], bs[4][64];
    const int lane = threadIdx.x & 63;
    const int w = threadIdx.x >> 6;
    const int o = blockIdx.x * 64 + lane;    // grid 512 -> 32768
    float f = 0.f;
    #pragma unroll
    for (int k = 0; k < 32; ++k) f += fwdp[(size_t)(w * 32 + k) * (NN * 4) + o];
    float b = 0.f;
    #pragma unroll
    for (int k = 0; k < 2; ++k) b += bwdp[(size_t)(w * 2 + k) * (NN * 4) + o];
    fs[w][lane] = f; bs[w][lane] = b;
    __syncthreads();
    if (threadIdx.x < 64) {
        const float F = (fs[0][lane] + fs[1][lane]) + (fs[2][lane] + fs[3][lane]);
        const float B = (bs[0][lane] + bs[1][lane]) + (bs[2][lane] + bs[3][lane]);
        const int r = o & 3;
        out[o] = B * modes[r * 3] + rc[o] * modes[r * 3 + 1] + F * modes[r * 3 + 2];
    }
}

// ==== fallback path (only if ws too small): zero + r4-proven fused k_link ====
__global__ void k_zero_fb(float* __restrict__ p, int n) {
    int i = blockIdx.x * 256 + threadIdx.x;
    if (i < n) p[i] = 0.f;
}

__global__ __launch_bounds__(256, 4) void k_link(
    const float* __restrict__ link, const float* __restrict__ ww,
    const float* __restrict__ prec, const float* __restrict__ rw,
    float* __restrict__ nl_out, float* __restrict__ fwd, float* __restrict__ bwd)
{
    __shared__ float part[64][16][4];
    __shared__ float fl[4][256][4];
    const int lane = threadIdx.x & 63;
    const int w = threadIdx.x >> 6;
    const int j = blockIdx.x * 256 + lane * 4;
    const float4 wwj = *(const float4*)&ww[j];
    const float4 pj  = *(const float4*)&prec[j];
    const float4 rwj0 = *(const float4*)&rw[j * 4];
    const float4 rwj1 = *(const float4*)&rw[j * 4 + 4];
    const float4 rwj2 = *(const float4*)&rw[j * 4 + 8];
    const float4 rwj3 = *(const float4*)&rw[j * 4 + 12];
    float fa[4][4];
    #pragma unroll
    for (int a = 0; a < 4; a++)
        #pragma unroll
        for (int r = 0; r < 4; r++) fa[a][r] = 0.f;
    for (int sub = 0; sub < 4; ++sub) {
        const int i00 = blockIdx.y * 256 + sub * 64;
        const int irow0 = i00 + w * 16;
        #pragma unroll 4
        for (int t = 0; t < 16; ++t) {
            const int i = irow0 + t;
            const float wwi = ww[i];
            const float4 rwi = *(const float4*)&rw[i * 4];
            const size_t off = (size_t)i * NN + j;
            const float4 Lv = *(const float4*)&link[off];
            const float c0 = 1.f - wwi;
            float4 e;
            e.x = (c0 - wwj.x) * Lv.x + wwi * pj.x;
            e.y = (c0 - wwj.y) * Lv.y + wwi * pj.y;
            e.z = (c0 - wwj.z) * Lv.z + wwi * pj.z;
            e.w = (c0 - wwj.w) * Lv.w + wwi * pj.w;
            *(float4*)&nl_out[off] = e;
            fa[0][0] += e.x * rwi.x; fa[0][1] += e.x * rwi.y; fa[0][2] += e.x * rwi.z; fa[0][3] += e.x * rwi.w;
            fa[1][0] += e.y * rwi.x; fa[1][1] += e.y * rwi.y; fa[1][2] += e.y * rwi.z; fa[1][3] += e.y * rwi.w;
            fa[2][0] += e.z * rwi.x; fa[2][1] += e.z * rwi.y; fa[2][2] += e.z * rwi.z; fa[2][3] += e.z * rwi.w;
            fa[3][0] += e.w * rwi.x; fa[3][1] += e.w * rwi.y; fa[3][2] += e.w * rwi.z; fa[3][3] += e.w * rwi.w;
            float b0 = e.x * rwj0.x + e.y * rwj1.x + e.z * rwj2.x + e.w * rwj3.x;
            float b1 = e.x * rwj0.y + e.y * rwj1.y + e.z * rwj2.y + e.w * rwj3.y;
            float b2 = e.x * rwj0.z + e.y * rwj1.z + e.z * rwj2.z + e.w * rwj3.z;
            float b3 = e.x * rwj0.w + e.y * rwj1.w + e.z * rwj2.w + e.w * rwj3.w;
            float u01 = (lane & 1) ? b0 : b1;
            float v01 = __shfl_xor(u01, 1);
            float A = ((lane & 1) ? b1 : b0) + v01;
            float u23 = (lane & 1) ? b2 : b3;
            float v23 = __shfl_xor(u23, 1);
            float B = ((lane & 1) ? b3 : b2) + v23;
            float uu = (lane & 2) ? A : B;
            float vv = __shfl_xor(uu, 2);
            float S = ((lane & 2) ? B : A) + vv;
            #pragma unroll
            for (int s = 4; s < 64; s <<= 1) S += __shfl_xor(S, s);
            const int row = w * 16 + t;
            if (lane < 4) part[row][((lane >> 2) + row) & 15][lane & 3] = S;
        }
        __syncthreads();
        if (threadIdx.x < 64) {
            const int row = threadIdx.x;
            float4 acc; acc.x = 0.f; acc.y = 0.f; acc.z = 0.f; acc.w = 0.f;
            #pragma unroll
            for (int k = 0; k < 16; ++k) {
                const float4 p = *(const float4*)&part[row][(k + row) & 15][0];
                acc.x += p.x; acc.y += p.y; acc.z += p.z; acc.w += p.w;
            }
            const int i = i00 + row;
            atomicAdd(&bwd[i * 4 + 0], acc.x);
            atomicAdd(&bwd[i * 4 + 1], acc.y);
            atomicAdd(&bwd[i * 4 + 2], acc.z);
            atomicAdd(&bwd[i * 4 + 3], acc.w);
        }
        __syncthreads();
    }
    #pragma unroll
    for (int a = 0; a < 4; a++)
        #pragma unroll
        for (int r = 0; r < 4; r++)
            fl[w][lane * 4 + a][r] = fa[a][r];
    __syncthreads();
    const int col = threadIdx.x;
    const float4 s0 = *(const float4*)&fl[0][col][0];
    const float4 s1 = *(const float4*)&fl[1][col][0];
    const float4 s2 = *(const float4*)&fl[2][col][0];
    const float4 s3 = *(const float4*)&fl[3][col][0];
    atomicAdd(&fwd[(blockIdx.x * 256 + col) * 4 + 0], s0.x + s1.x + s2.x + s3.x);
    atomicAdd(&fwd[(blockIdx.x * 256 + col) * 4 + 1], s0.y + s1.y + s2.y + s3.y);
    atomicAdd(&fwd[(blockIdx.x * 256 + col) * 4 + 2], s0.z + s1.z + s2.z + s3.z);
    atomicAdd(&fwd[(blockIdx.x * 256 + col) * 4 + 3], s0.w + s1.w + s2.w + s3.w);
}

__global__ void k_final(const float* __restrict__ fwd, const float* __restrict__ bwd,
                        const float* __restrict__ rc, const float* __restrict__ modes,
                        float* __restrict__ out) {
    int idx = blockIdx.x * 256 + threadIdx.x;
    int r = idx & 3;
    float m0 = modes[r * 3], m1 = modes[r * 3 + 1], m2 = modes[r * 3 + 2];
    out[idx] = bwd[idx] * m0 + rc[idx] * m1 + fwd[idx] * m2;
}

extern "C" void kernel_launch(void* const* d_in, const int* in_sizes, int n_in,
                              void* d_out, int out_size, void* d_ws, size_t ws_size,
                              hipStream_t stream) {
    const float* mem   = (const float*)d_in[0];
    const float* u     = (const float*)d_in[1];
    const float* prec  = (const float*)d_in[2];
    const float* link  = (const float*)d_in[3];
    const float* rw    = (const float*)d_in[4];
    const float* rk    = (const float*)d_in[5];
    const float* rstr  = (const float*)d_in[6];
    const float* wk    = (const float*)d_in[7];
    const float* wstr  = (const float*)d_in[8];
    const float* er    = (const float*)d_in[9];
    const float* wv    = (const float*)d_in[10];
    const float* fg    = (const float*)d_in[11];
    const float* ag    = (const float*)d_in[12];
    const float* wg    = (const float*)d_in[13];
    const float* modes = (const float*)d_in[14];
    float* out = (float*)d_out;
    float* ws  = (float*)d_ws;
    float* nlr = out + O_NL;

    k_stats_apart<<<768, 256, 0, stream>>>(mem, rw, wk, fg, wstr, u,
                                           nlr + P_RVP, ws + S_LOGITS, ws + S_RET,
                                           nlr + P_SE, nlr + P_APART, nlr + P_CPART);
    k_grank<<<32, 256, 0, stream>>>(u, nlr + P_APART, nlr + P_CPART, nlr + P_RVP,
                                    nlr + P_SE, ws + S_G, (int*)(ws + S_RANK),
                                    nlr + P_GS, ws + S_SCAL, out + O_RV);
    k_scatter<<<32, 256, 0, stream>>>(ws + S_G, (const int*)(ws + S_RANK),
                                      nlr + P_GS, ws + S_ALLOC, ws + S_SCAL);
    k_rownew<<<512, 256, 0, stream>>>(mem, ws + S_LOGITS, ws + S_ALLOC, u, ws + S_RET,
                                      prec, er, wv, rk, rstr, ag, wg, ws + S_SCAL,
                                      ws + S_WW, out + O_NM, out + O_NU, out + O_NP, ws + S_RC);

    if (ws_size >= WS_NEED2) {
        k_link6<<<1024, 256, 0, stream>>>(link, ws + S_WW, prec, rw, out + O_NL,
                                          ws + S_FWDP2, ws + S_BWDP2);
        k_final6<<<512, 256, 0, stream>>>(ws + S_FWDP2, ws + S_BWDP2, ws + S_RC, modes, out + O_NR);
    } else {
        k_zero_fb<<<257, 256, 0, stream>>>(ws + S_FWD, 65568);
        dim3 lg(32, 32);
        k_link<<<lg, 256, 0, stream>>>(link, ws + S_WW, prec, rw, out + O_NL,
                                       ws + S_FWD, ws + S_BWD);
        k_final<<<128, 256, 0, stream>>>(ws + S_FWD, ws + S_BWD, ws + S_RC, modes, out + O_NR);
    }
}